// Round 1
// baseline (682.967 us; speedup 1.0000x reference)
//
#include <hip/hip_runtime.h>
#include <math.h>

// ---------------- helpers ----------------
static __device__ __forceinline__ float lrelu(float x){ return x > 0.f ? x : 0.2f*x; }
static __device__ __forceinline__ float eluf(float x){ return x > 0.f ? x : expm1f(x); }
static __device__ __forceinline__ float sel4(float a,float b,float c,float d,int i){
  float lo = (i&1)? b : a; float hi = (i&1)? d : c; return (i&2)? hi : lo;
}
static __device__ __forceinline__ float sel2(float a,float b,int i){ return (i&1)? b : a; }
static __device__ __forceinline__ float wred_max(float v){
  v = fmaxf(v, __shfl_xor(v, 32)); v = fmaxf(v, __shfl_xor(v, 16));
  v = fmaxf(v, __shfl_xor(v, 8));  v = fmaxf(v, __shfl_xor(v, 4));
  v = fmaxf(v, __shfl_xor(v, 2));  v = fmaxf(v, __shfl_xor(v, 1));
  return v;
}
static __device__ __forceinline__ float wred_sum(float v){
  v += __shfl_xor(v, 32); v += __shfl_xor(v, 16); v += __shfl_xor(v, 8);
  v += __shfl_xor(v, 4);  v += __shfl_xor(v, 2);  v += __shfl_xor(v, 1);
  return v;
}

// ---------------- edge decode + CSR build ----------------
// Detect int64 vs int32 edge_index: for int64 (values < 2^31), every odd int32
// word is a zero high-word. 64 odd words all zero => int64.
__global__ void k_detect(const int* __restrict__ ei, int* __restrict__ flag){
  int lane = threadIdx.x;
  int w = ei[2*lane + 1];
  unsigned long long b = __ballot(w != 0);
  if (lane == 0) flag[0] = (b == 0ull) ? 1 : 0;   // 1 => int64
}

__global__ void k_decode(const void* __restrict__ ei, const int* __restrict__ flag,
                         int* __restrict__ srcd, int* __restrict__ dstd,
                         int* __restrict__ cnt, int E){
  int e = blockIdx.x*blockDim.x + threadIdx.x;
  if (e >= E) return;
  int s, d;
  if (flag[0]) {
    const long long* p = (const long long*)ei;
    s = (int)p[e]; d = (int)p[(size_t)E + e];
  } else {
    const int* p = (const int*)ei;
    s = p[e]; d = p[(size_t)E + e];
  }
  srcd[e] = s; dstd[e] = d;
  atomicAdd(&cnt[d], 1);
}

#define SCAN_T 256
#define SCAN_I 4
__global__ void k_scan1(const int* __restrict__ cnt, int* __restrict__ rp,
                        int* __restrict__ bsum, int N){
  __shared__ int sh[SCAN_T];
  int t = threadIdx.x, b = blockIdx.x;
  int base = b*SCAN_T*SCAN_I + t*SCAN_I;
  int v[SCAN_I]; int s = 0;
  #pragma unroll
  for (int i=0;i<SCAN_I;i++){ int idx = base+i; v[i] = (idx<N)? cnt[idx] : 0; s += v[i]; }
  sh[t] = s; __syncthreads();
  for (int off=1; off<SCAN_T; off<<=1){
    int add = (t>=off) ? sh[t-off] : 0;
    __syncthreads();
    sh[t] += add;
    __syncthreads();
  }
  int ebase = sh[t] - s;   // exclusive base for this thread
  int p = 0;
  #pragma unroll
  for (int i=0;i<SCAN_I;i++){ int idx = base+i; if (idx<N) rp[idx] = ebase + p; p += v[i]; }
  if (t == SCAN_T-1) bsum[b] = sh[t];
}

__global__ void k_scan2(int* __restrict__ bsum, int NB){
  __shared__ int sh[SCAN_T];
  int t = threadIdx.x;
  int s = (t < NB) ? bsum[t] : 0;
  sh[t] = s; __syncthreads();
  for (int off=1; off<SCAN_T; off<<=1){
    int add = (t>=off) ? sh[t-off] : 0;
    __syncthreads();
    sh[t] += add;
    __syncthreads();
  }
  if (t < NB) bsum[t] = sh[t] - s;  // exclusive
}

__global__ void k_scan3(int* __restrict__ rp, int* __restrict__ cur,
                        const int* __restrict__ bsum, int N, int E){
  int idx = blockIdx.x*blockDim.x + threadIdx.x;
  if (idx == 0) rp[N] = E;
  if (idx >= N) return;
  int v = rp[idx] + bsum[idx >> 10];   // 1024 elems per scan1 block
  rp[idx] = v; cur[idx] = v;
}

__global__ void k_scatter(const int* __restrict__ srcd, const int* __restrict__ dstd,
                          int* __restrict__ cur, int* __restrict__ csr, int E){
  int e = blockIdx.x*blockDim.x + threadIdx.x;
  if (e >= E) return;
  int d = dstd[e];
  int p = atomicAdd(&cur[d], 1);
  csr[p] = srcd[e];
}

// ---------------- GEMMs (h = x @ W), fp32 vector ALU ----------------
// Layer 1: Fin=128, HO=128. 32 rows x 128 cols per block, 256 thr, 4x4 microtile.
__global__ __launch_bounds__(256) void k_gemm1(const float* __restrict__ x,
                                               const float* __restrict__ W,
                                               float* __restrict__ h, int N){
  __shared__ float xs[32*128];
  int t = threadIdx.x;
  int r0 = blockIdx.x*32;
  {
    int row = t>>5, k4 = (t&31)*4;
    #pragma unroll
    for (int p=0;p<4;p++, row+=8){
      int gr = r0+row;
      float4 v = make_float4(0.f,0.f,0.f,0.f);
      if (gr < N) v = *(const float4*)&x[gr*128 + k4];
      *(float4*)&xs[row*128 + k4] = v;
    }
  }
  __syncthreads();
  int tc = (t&31)*4, tr = (t>>5)*4;
  float acc[4][4];
  #pragma unroll
  for (int i=0;i<4;i++){ acc[i][0]=0.f; acc[i][1]=0.f; acc[i][2]=0.f; acc[i][3]=0.f; }
  #pragma unroll 4
  for (int k=0;k<128;k++){
    float4 wv = *(const float4*)&W[k*128 + tc];
    #pragma unroll
    for (int i=0;i<4;i++){
      float xv = xs[(tr+i)*128 + k];
      acc[i][0] += xv*wv.x; acc[i][1] += xv*wv.y;
      acc[i][2] += xv*wv.z; acc[i][3] += xv*wv.w;
    }
  }
  #pragma unroll
  for (int i=0;i<4;i++){
    int gr = r0 + tr + i;
    if (gr < N)
      *(float4*)&h[gr*128 + tc] = make_float4(acc[i][0],acc[i][1],acc[i][2],acc[i][3]);
  }
}

// Layer 2: Fin=128, HO=32. 64 rows x 32 cols per block, 128 thr, 4x4 microtile.
#define G2PAD 132   // pad: lane groups land on 2 banks -> 4-way max, writes stay 16B-aligned
__global__ __launch_bounds__(128) void k_gemm2(const float* __restrict__ x,
                                               const float* __restrict__ W,
                                               float* __restrict__ h, int N){
  __shared__ float xs[64*G2PAD];
  int t = threadIdx.x;
  int r0 = blockIdx.x*64;
  {
    int row = t>>5, k4 = (t&31)*4;
    #pragma unroll
    for (int p=0;p<16;p++, row+=4){
      int gr = r0+row;
      float4 v = make_float4(0.f,0.f,0.f,0.f);
      if (gr < N) v = *(const float4*)&x[gr*128 + k4];
      *(float4*)&xs[row*G2PAD + k4] = v;
    }
  }
  __syncthreads();
  int tc = (t&7)*4, tr = (t>>3)*4;
  float acc[4][4];
  #pragma unroll
  for (int i=0;i<4;i++){ acc[i][0]=0.f; acc[i][1]=0.f; acc[i][2]=0.f; acc[i][3]=0.f; }
  #pragma unroll 4
  for (int k=0;k<128;k++){
    float4 wv = *(const float4*)&W[k*32 + tc];
    #pragma unroll
    for (int i=0;i<4;i++){
      float xv = xs[(tr+i)*G2PAD + k];
      acc[i][0] += xv*wv.x; acc[i][1] += xv*wv.y;
      acc[i][2] += xv*wv.z; acc[i][3] += xv*wv.w;
    }
  }
  #pragma unroll
  for (int i=0;i<4;i++){
    int gr = r0 + tr + i;
    if (gr < N)
      *(float4*)&h[gr*32 + tc] = make_float4(acc[i][0],acc[i][1],acc[i][2],acc[i][3]);
  }
}

// Layer 3: Fin=32, HO=2 (tiny). One thread per row; also emits a_src/a_dst.
__global__ void k_gemm3(const float* __restrict__ x, const float* __restrict__ W,
                        const float* __restrict__ atts, const float* __restrict__ attd,
                        float* __restrict__ h, float* __restrict__ as_,
                        float* __restrict__ ad_, int N){
  int n = blockIdx.x*blockDim.x + threadIdx.x;
  if (n >= N) return;
  const float* xr = x + n*32;
  float a0 = 0.f, a1 = 0.f;
  #pragma unroll
  for (int k=0;k<32;k++){ float xv = xr[k]; a0 += xv*W[2*k]; a1 += xv*W[2*k+1]; }
  h[2*n] = a0; h[2*n+1] = a1;
  as_[n] = a0*atts[0] + a1*atts[1];
  ad_[n] = a0*attd[0] + a1*attd[1];
}

// a_src/a_dst terms: one thread per (node, head); h row slice is contiguous.
template<int H, int O>
__global__ void k_att(const float* __restrict__ h, const float* __restrict__ atts,
                      const float* __restrict__ attd, float* __restrict__ as_,
                      float* __restrict__ ad_, int N){
  int u = blockIdx.x*blockDim.x + threadIdx.x;
  if (u >= N*H) return;
  int hh = u & (H-1);
  const float* hr = h + (size_t)u*O;     // u = n*H + hh  ->  h + n*H*O + hh*O
  const float* sa = atts + hh*O;
  const float* da = attd + hh*O;
  float ss = 0.f, dd = 0.f;
  #pragma unroll
  for (int o=0;o<O;o+=4){
    float4 hv = *(const float4*)&hr[o];
    float4 sv = *(const float4*)&sa[o];
    float4 dv = *(const float4*)&da[o];
    ss += hv.x*sv.x + hv.y*sv.y + hv.z*sv.z + hv.w*sv.w;
    dd += hv.x*dv.x + hv.y*dv.y + hv.z*dv.z + hv.w*dv.w;
  }
  as_[u] = ss; ad_[u] = dd;
}

// ---------------- aggregation (one wave per dst node) ----------------
// Layer 1: H=4, O=32 (row = 128 floats). Phase3: 2 edges/wave, float4/lane.
__global__ __launch_bounds__(256) void k_agg1(const int* __restrict__ rp, const int* __restrict__ csr,
    const float* __restrict__ as_, const float* __restrict__ ad_,
    const float* __restrict__ h, const float* __restrict__ bias,
    float* __restrict__ out, int N){
  int n = blockIdx.x*4 + (threadIdx.x>>6);
  if (n >= N) return;
  int lane = threadIdx.x & 63;
  int start = rp[n], end = rp[n+1];
  float4 ad  = *(const float4*)&ad_[n*4];
  float4 asl = *(const float4*)&as_[n*4];
  float sl0 = lrelu(asl.x+ad.x), sl1 = lrelu(asl.y+ad.y);
  float sl2 = lrelu(asl.z+ad.z), sl3 = lrelu(asl.w+ad.w);
  // phase 1: max
  float m0=sl0, m1=sl1, m2=sl2, m3=sl3;
  for (int i=start+lane; i<end; i+=64){
    int s = csr[i];
    float4 av = *(const float4*)&as_[s*4];
    m0 = fmaxf(m0, lrelu(av.x+ad.x)); m1 = fmaxf(m1, lrelu(av.y+ad.y));
    m2 = fmaxf(m2, lrelu(av.z+ad.z)); m3 = fmaxf(m3, lrelu(av.w+ad.w));
  }
  m0 = wred_max(m0); m1 = wred_max(m1); m2 = wred_max(m2); m3 = wred_max(m3);
  // phase 2: denom
  float l0=0.f, l1=0.f, l2=0.f, l3=0.f;
  for (int i=start+lane; i<end; i+=64){
    int s = csr[i];
    float4 av = *(const float4*)&as_[s*4];
    l0 += __expf(lrelu(av.x+ad.x)-m0); l1 += __expf(lrelu(av.y+ad.y)-m1);
    l2 += __expf(lrelu(av.z+ad.z)-m2); l3 += __expf(lrelu(av.w+ad.w)-m3);
  }
  if (lane == 0){
    l0 += __expf(sl0-m0); l1 += __expf(sl1-m1);
    l2 += __expf(sl2-m2); l3 += __expf(sl3-m3);
  }
  l0 = wred_sum(l0); l1 = wred_sum(l1); l2 = wred_sum(l2); l3 = wred_sum(l3);
  // phase 3: weighted accumulate (2 edges concurrently)
  int half = lane>>5, li = lane&31, head = li>>3;
  float mh   = sel4(m0,m1,m2,m3,head);
  float invh = 1.f/sel4(l0,l1,l2,l3,head);
  float adh  = sel4(ad.x,ad.y,ad.z,ad.w,head);
  float slh  = sel4(sl0,sl1,sl2,sl3,head);
  const float4* h4 = (const float4*)h;
  float4 acc = make_float4(0.f,0.f,0.f,0.f);
  for (int i=start+half; i<end; i+=2){
    int s = csr[i];
    float w = __expf(lrelu(as_[s*4+head]+adh) - mh);
    float4 v = h4[s*32 + li];
    acc.x += w*v.x; acc.y += w*v.y; acc.z += w*v.z; acc.w += w*v.w;
  }
  if (half == 0){
    float w = __expf(slh - mh);
    float4 v = h4[n*32 + li];
    acc.x += w*v.x; acc.y += w*v.y; acc.z += w*v.z; acc.w += w*v.w;
  }
  acc.x += __shfl_xor(acc.x,32); acc.y += __shfl_xor(acc.y,32);
  acc.z += __shfl_xor(acc.z,32); acc.w += __shfl_xor(acc.w,32);
  if (half == 0){
    float4 bv = *(const float4*)&bias[li*4];
    float4 r;
    r.x = eluf(acc.x*invh + bv.x); r.y = eluf(acc.y*invh + bv.y);
    r.z = eluf(acc.z*invh + bv.z); r.w = eluf(acc.w*invh + bv.w);
    *(float4*)&out[n*128 + li*4] = r;
  }
}

// Layer 2: H=2, O=16 (row = 32 floats). Phase3: 8 edges/wave.
__global__ __launch_bounds__(256) void k_agg2(const int* __restrict__ rp, const int* __restrict__ csr,
    const float* __restrict__ as_, const float* __restrict__ ad_,
    const float* __restrict__ h, const float* __restrict__ bias,
    float* __restrict__ out, int N){
  int n = blockIdx.x*4 + (threadIdx.x>>6);
  if (n >= N) return;
  int lane = threadIdx.x & 63;
  int start = rp[n], end = rp[n+1];
  float2 ad  = *(const float2*)&ad_[n*2];
  float2 asl = *(const float2*)&as_[n*2];
  float sl0 = lrelu(asl.x+ad.x), sl1 = lrelu(asl.y+ad.y);
  float m0=sl0, m1=sl1;
  for (int i=start+lane; i<end; i+=64){
    int s = csr[i];
    float2 av = *(const float2*)&as_[s*2];
    m0 = fmaxf(m0, lrelu(av.x+ad.x)); m1 = fmaxf(m1, lrelu(av.y+ad.y));
  }
  m0 = wred_max(m0); m1 = wred_max(m1);
  float l0=0.f, l1=0.f;
  for (int i=start+lane; i<end; i+=64){
    int s = csr[i];
    float2 av = *(const float2*)&as_[s*2];
    l0 += __expf(lrelu(av.x+ad.x)-m0); l1 += __expf(lrelu(av.y+ad.y)-m1);
  }
  if (lane == 0){ l0 += __expf(sl0-m0); l1 += __expf(sl1-m1); }
  l0 = wred_sum(l0); l1 = wred_sum(l1);
  int grp = lane>>3, li = lane&7, head = li>>2;
  float mh   = sel2(m0,m1,head);
  float invh = 1.f/sel2(l0,l1,head);
  float adh  = sel2(ad.x,ad.y,head);
  float slh  = sel2(sl0,sl1,head);
  const float4* h4 = (const float4*)h;
  float4 acc = make_float4(0.f,0.f,0.f,0.f);
  for (int i=start+grp; i<end; i+=8){
    int s = csr[i];
    float w = __expf(lrelu(as_[s*2+head]+adh) - mh);
    float4 v = h4[s*8 + li];
    acc.x += w*v.x; acc.y += w*v.y; acc.z += w*v.z; acc.w += w*v.w;
  }
  if (grp == 0){
    float w = __expf(slh - mh);
    float4 v = h4[n*8 + li];
    acc.x += w*v.x; acc.y += w*v.y; acc.z += w*v.z; acc.w += w*v.w;
  }
  #pragma unroll
  for (int msk=8; msk<64; msk<<=1){
    acc.x += __shfl_xor(acc.x,msk); acc.y += __shfl_xor(acc.y,msk);
    acc.z += __shfl_xor(acc.z,msk); acc.w += __shfl_xor(acc.w,msk);
  }
  if (grp == 0){
    float4 bv = *(const float4*)&bias[li*4];
    float4 r;
    r.x = eluf(acc.x*invh + bv.x); r.y = eluf(acc.y*invh + bv.y);
    r.z = eluf(acc.z*invh + bv.z); r.w = eluf(acc.w*invh + bv.w);
    *(float4*)&out[n*32 + li*4] = r;
  }
}

// Layer 3: H=1, O=2. One lane per edge; fused bias + log_softmax epilogue.
__global__ __launch_bounds__(256) void k_agg3(const int* __restrict__ rp, const int* __restrict__ csr,
    const float* __restrict__ as_, const float* __restrict__ ad_,
    const float* __restrict__ h, const float* __restrict__ bias,
    float* __restrict__ out, int N){
  int n = blockIdx.x*4 + (threadIdx.x>>6);
  if (n >= N) return;
  int lane = threadIdx.x & 63;
  int start = rp[n], end = rp[n+1];
  float adh = ad_[n];
  float sl = lrelu(as_[n] + adh);
  float m = sl;
  for (int i=start+lane; i<end; i+=64){
    int s = csr[i];
    m = fmaxf(m, lrelu(as_[s] + adh));
  }
  m = wred_max(m);
  const float2* h2 = (const float2*)h;
  float l = 0.f;
  float2 acc = make_float2(0.f, 0.f);
  for (int i=start+lane; i<end; i+=64){
    int s = csr[i];
    float w = __expf(lrelu(as_[s] + adh) - m);
    l += w;
    float2 v = h2[s];
    acc.x += w*v.x; acc.y += w*v.y;
  }
  if (lane == 0){
    float w = __expf(sl - m);
    l += w;
    float2 v = h2[n];
    acc.x += w*v.x; acc.y += w*v.y;
  }
  l = wred_sum(l);
  acc.x = wred_sum(acc.x); acc.y = wred_sum(acc.y);
  if (lane == 0){
    float inv = 1.f/l;
    float g0 = acc.x*inv + bias[0];
    float g1 = acc.y*inv + bias[1];
    float mm = fmaxf(g0, g1);
    float lse = mm + logf(__expf(g0-mm) + __expf(g1-mm));
    *(float2*)&out[2*n] = make_float2(g0-lse, g1-lse);
  }
}

// ---------------- launch ----------------
extern "C" void kernel_launch(void* const* d_in, const int* in_sizes, int n_in,
                              void* d_out, int out_size, void* d_ws, size_t ws_size,
                              hipStream_t stream) {
  const float* x   = (const float*)d_in[0];
  const void*  ei  = d_in[1];
  const float* W1  = (const float*)d_in[2];
  const float* as1 = (const float*)d_in[3];
  const float* ad1 = (const float*)d_in[4];
  const float* b1  = (const float*)d_in[5];
  const float* W2  = (const float*)d_in[6];
  const float* as2 = (const float*)d_in[7];
  const float* ad2 = (const float*)d_in[8];
  const float* b2  = (const float*)d_in[9];
  const float* W3  = (const float*)d_in[10];
  const float* as3 = (const float*)d_in[11];
  const float* ad3 = (const float*)d_in[12];
  const float* b3  = (const float*)d_in[13];

  int N = in_sizes[0] / 128;
  int E = in_sizes[1] / 2;

  char* w = (char*)d_ws;
  size_t off = 0;
  auto alloc = [&](size_t bytes)->void*{
    void* p = w + off; off += (bytes + 255) & ~(size_t)255; return p;
  };
  int*   flag   = (int*)alloc(256);
  int*   bsum   = (int*)alloc(4096);
  int*   cnt    = (int*)alloc((size_t)N*4);
  int*   rp     = (int*)alloc((size_t)(N+1)*4);
  int*   cur    = (int*)alloc((size_t)N*4);
  int*   srcd   = (int*)alloc((size_t)E*4);
  int*   dstd   = (int*)alloc((size_t)E*4);
  int*   csr    = (int*)alloc((size_t)E*4);
  float* as_buf = (float*)alloc((size_t)N*4*4);
  float* ad_buf = (float*)alloc((size_t)N*4*4);
  float* hbuf   = (float*)alloc((size_t)N*128*4);
  float* xbuf   = (float*)alloc((size_t)N*128*4);
  if (off > ws_size) return;  // workspace too small -> visible failure

  hipMemsetAsync(cnt, 0, (size_t)N*4, stream);
  k_detect<<<1, 64, 0, stream>>>((const int*)ei, flag);
  int eb = (E + 255)/256;
  k_decode<<<eb, 256, 0, stream>>>(ei, flag, srcd, dstd, cnt, E);
  int nb1 = (N + 1023)/1024;
  k_scan1<<<nb1, 256, 0, stream>>>(cnt, rp, bsum, N);
  k_scan2<<<1, 256, 0, stream>>>(bsum, nb1);
  k_scan3<<<(N + 255)/256, 256, 0, stream>>>(rp, cur, bsum, N, E);
  k_scatter<<<eb, 256, 0, stream>>>(srcd, dstd, cur, csr, E);

  // layer 1: Fin=128, H=4, O=32, concat, ELU
  k_gemm1<<<(N + 31)/32, 256, 0, stream>>>(x, W1, hbuf, N);
  k_att<4,32><<<(N*4 + 255)/256, 256, 0, stream>>>(hbuf, as1, ad1, as_buf, ad_buf, N);
  k_agg1<<<(N + 3)/4, 256, 0, stream>>>(rp, csr, as_buf, ad_buf, hbuf, b1, xbuf, N);

  // layer 2: Fin=128, H=2, O=16, concat, ELU
  k_gemm2<<<(N + 63)/64, 128, 0, stream>>>(xbuf, W2, hbuf, N);
  k_att<2,16><<<(N*2 + 255)/256, 256, 0, stream>>>(hbuf, as2, ad2, as_buf, ad_buf, N);
  k_agg2<<<(N + 3)/4, 256, 0, stream>>>(rp, csr, as_buf, ad_buf, hbuf, b2, xbuf, N);

  // layer 3: Fin=32, H=1, O=2, mean(=identity), bias + log_softmax
  k_gemm3<<<(N + 255)/256, 256, 0, stream>>>(xbuf, W3, as3, ad3, hbuf, as_buf, ad_buf, N);
  k_agg3<<<(N + 3)/4, 256, 0, stream>>>(rp, csr, as_buf, ad_buf, hbuf, b3, (float*)d_out, N);
}

// Round 2
// 633.360 us; speedup vs baseline: 1.0783x; 1.0783x over previous
//
#include <hip/hip_runtime.h>
#include <math.h>

// ---------------- helpers ----------------
static __device__ __forceinline__ float lrelu(float x){ return x > 0.f ? x : 0.2f*x; }
static __device__ __forceinline__ float eluf(float x){ return x > 0.f ? x : expm1f(x); }
static __device__ __forceinline__ float sel4(float a,float b,float c,float d,int i){
  float lo = (i&1)? b : a; float hi = (i&1)? d : c; return (i&2)? hi : lo;
}
static __device__ __forceinline__ float sel2(float a,float b,int i){ return (i&1)? b : a; }
static __device__ __forceinline__ float wred_sum(float v){
  v += __shfl_xor(v, 32); v += __shfl_xor(v, 16); v += __shfl_xor(v, 8);
  v += __shfl_xor(v, 4);  v += __shfl_xor(v, 2);  v += __shfl_xor(v, 1);
  return v;
}
static __device__ __forceinline__ unsigned short f2bf(float f){
  unsigned int u = __float_as_uint(f);
  unsigned int r = (u + 0x7FFFu + ((u>>16)&1u)) >> 16;   // round-nearest-even
  return (unsigned short)r;
}
static __device__ __forceinline__ float bf2f(unsigned short s){
  return __uint_as_float(((unsigned int)s)<<16);
}

// ---------------- edge decode + CSR build ----------------
// Detect int64 vs int32 edge_index: for int64 (values < 2^31), every odd int32
// word is a zero high-word.
__global__ void k_detect(const int* __restrict__ ei, int* __restrict__ flag){
  int lane = threadIdx.x;
  int w = ei[2*lane + 1];
  unsigned long long b = __ballot(w != 0);
  if (lane == 0) flag[0] = (b == 0ull) ? 1 : 0;   // 1 => int64
}

__global__ void k_count(const void* __restrict__ ei, const int* __restrict__ flag,
                        int* __restrict__ cnt, int E){
  int e = blockIdx.x*blockDim.x + threadIdx.x;
  if (e >= E) return;
  int d;
  if (flag[0]) d = (int)((const long long*)ei)[(size_t)E + e];
  else         d = ((const int*)ei)[(size_t)E + e];
  atomicAdd(&cnt[d], 1);
}

#define SCAN_T 256
#define SCAN_I 4
__global__ void k_scan1(const int* __restrict__ cnt, int* __restrict__ rp,
                        int* __restrict__ bsum, int N){
  __shared__ int sh[SCAN_T];
  int t = threadIdx.x, b = blockIdx.x;
  int base = b*SCAN_T*SCAN_I + t*SCAN_I;
  int v[SCAN_I]; int s = 0;
  #pragma unroll
  for (int i=0;i<SCAN_I;i++){ int idx = base+i; v[i] = (idx<N)? cnt[idx] : 0; s += v[i]; }
  sh[t] = s; __syncthreads();
  for (int off=1; off<SCAN_T; off<<=1){
    int add = (t>=off) ? sh[t-off] : 0;
    __syncthreads();
    sh[t] += add;
    __syncthreads();
  }
  int ebase = sh[t] - s;
  int p = 0;
  #pragma unroll
  for (int i=0;i<SCAN_I;i++){ int idx = base+i; if (idx<N) rp[idx] = ebase + p; p += v[i]; }
  if (t == SCAN_T-1) bsum[b] = sh[t];
}

__global__ void k_scan2(int* __restrict__ bsum, int NB){
  __shared__ int sh[SCAN_T];
  int t = threadIdx.x;
  int s = (t < NB) ? bsum[t] : 0;
  sh[t] = s; __syncthreads();
  for (int off=1; off<SCAN_T; off<<=1){
    int add = (t>=off) ? sh[t-off] : 0;
    __syncthreads();
    sh[t] += add;
    __syncthreads();
  }
  if (t < NB) bsum[t] = sh[t] - s;
}

__global__ void k_scan3(int* __restrict__ rp, int* __restrict__ cur,
                        const int* __restrict__ bsum, int N, int E){
  int idx = blockIdx.x*blockDim.x + threadIdx.x;
  if (idx == 0) rp[N] = E;
  if (idx >= N) return;
  int v = rp[idx] + bsum[idx >> 10];
  rp[idx] = v; cur[idx] = v;
}

__global__ void k_scatter(const void* __restrict__ ei, const int* __restrict__ flag,
                          int* __restrict__ cur, int* __restrict__ csr, int E){
  int e = blockIdx.x*blockDim.x + threadIdx.x;
  if (e >= E) return;
  int s, d;
  if (flag[0]) {
    const long long* p = (const long long*)ei;
    s = (int)p[e]; d = (int)p[(size_t)E + e];
  } else {
    const int* p = (const int*)ei;
    s = p[e]; d = p[(size_t)E + e];
  }
  int pos = atomicAdd(&cur[d], 1);
  csr[pos] = s;
}

// ---------------- GEMMs (h = x @ W), fp32 vector ALU ----------------
__global__ __launch_bounds__(256) void k_gemm1(const float* __restrict__ x,
                                               const float* __restrict__ W,
                                               float* __restrict__ h, int N){
  __shared__ float xs[32*128];
  int t = threadIdx.x;
  int r0 = blockIdx.x*32;
  {
    int row = t>>5, k4 = (t&31)*4;
    #pragma unroll
    for (int p=0;p<4;p++, row+=8){
      int gr = r0+row;
      float4 v = make_float4(0.f,0.f,0.f,0.f);
      if (gr < N) v = *(const float4*)&x[gr*128 + k4];
      *(float4*)&xs[row*128 + k4] = v;
    }
  }
  __syncthreads();
  int tc = (t&31)*4, tr = (t>>5)*4;
  float acc[4][4];
  #pragma unroll
  for (int i=0;i<4;i++){ acc[i][0]=0.f; acc[i][1]=0.f; acc[i][2]=0.f; acc[i][3]=0.f; }
  #pragma unroll 4
  for (int k=0;k<128;k++){
    float4 wv = *(const float4*)&W[k*128 + tc];
    #pragma unroll
    for (int i=0;i<4;i++){
      float xv = xs[(tr+i)*128 + k];
      acc[i][0] += xv*wv.x; acc[i][1] += xv*wv.y;
      acc[i][2] += xv*wv.z; acc[i][3] += xv*wv.w;
    }
  }
  #pragma unroll
  for (int i=0;i<4;i++){
    int gr = r0 + tr + i;
    if (gr < N)
      *(float4*)&h[gr*128 + tc] = make_float4(acc[i][0],acc[i][1],acc[i][2],acc[i][3]);
  }
}

#define G2PAD 132
__global__ __launch_bounds__(128) void k_gemm2(const float* __restrict__ x,
                                               const float* __restrict__ W,
                                               float* __restrict__ h, int N){
  __shared__ float xs[64*G2PAD];
  int t = threadIdx.x;
  int r0 = blockIdx.x*64;
  {
    int row = t>>5, k4 = (t&31)*4;
    #pragma unroll
    for (int p=0;p<16;p++, row+=4){
      int gr = r0+row;
      float4 v = make_float4(0.f,0.f,0.f,0.f);
      if (gr < N) v = *(const float4*)&x[gr*128 + k4];
      *(float4*)&xs[row*G2PAD + k4] = v;
    }
  }
  __syncthreads();
  int tc = (t&7)*4, tr = (t>>3)*4;
  float acc[4][4];
  #pragma unroll
  for (int i=0;i<4;i++){ acc[i][0]=0.f; acc[i][1]=0.f; acc[i][2]=0.f; acc[i][3]=0.f; }
  #pragma unroll 4
  for (int k=0;k<128;k++){
    float4 wv = *(const float4*)&W[k*32 + tc];
    #pragma unroll
    for (int i=0;i<4;i++){
      float xv = xs[(tr+i)*G2PAD + k];
      acc[i][0] += xv*wv.x; acc[i][1] += xv*wv.y;
      acc[i][2] += xv*wv.z; acc[i][3] += xv*wv.w;
    }
  }
  #pragma unroll
  for (int i=0;i<4;i++){
    int gr = r0 + tr + i;
    if (gr < N)
      *(float4*)&h[gr*32 + tc] = make_float4(acc[i][0],acc[i][1],acc[i][2],acc[i][3]);
  }
}

// Layer 3 GEMM: Fin=32, HO=2. One thread per row; emits a_src/a_dst directly.
__global__ void k_gemm3(const float* __restrict__ x, const float* __restrict__ W,
                        const float* __restrict__ atts, const float* __restrict__ attd,
                        float* __restrict__ h, float* __restrict__ as_,
                        float* __restrict__ ad_, int N){
  int n = blockIdx.x*blockDim.x + threadIdx.x;
  if (n >= N) return;
  const float* xr = x + n*32;
  float a0 = 0.f, a1 = 0.f;
  #pragma unroll
  for (int k=0;k<32;k++){ float xv = xr[k]; a0 += xv*W[2*k]; a1 += xv*W[2*k+1]; }
  h[2*n] = a0; h[2*n+1] = a1;
  as_[n] = a0*atts[0] + a1*atts[1];
  ad_[n] = a0*attd[0] + a1*attd[1];
}

// a_src/a_dst + bf16 conversion of h (h row slice is contiguous per (n,head)).
template<int H, int O>
__global__ void k_att(const float* __restrict__ h, const float* __restrict__ atts,
                      const float* __restrict__ attd, float* __restrict__ as_,
                      float* __restrict__ ad_, unsigned short* __restrict__ hb, int N){
  int u = blockIdx.x*blockDim.x + threadIdx.x;
  if (u >= N*H) return;
  int hh = u & (H-1);
  const float* hr = h + (size_t)u*O;
  unsigned short* hbr = hb + (size_t)u*O;
  const float* sa = atts + hh*O;
  const float* da = attd + hh*O;
  float ss = 0.f, dd = 0.f;
  #pragma unroll
  for (int o=0;o<O;o+=4){
    float4 hv = *(const float4*)&hr[o];
    float4 sv = *(const float4*)&sa[o];
    float4 dv = *(const float4*)&da[o];
    ss += hv.x*sv.x + hv.y*sv.y + hv.z*sv.z + hv.w*sv.w;
    dd += hv.x*dv.x + hv.y*dv.y + hv.z*dv.z + hv.w*dv.w;
    ushort4 bv;
    bv.x = f2bf(hv.x); bv.y = f2bf(hv.y); bv.z = f2bf(hv.z); bv.w = f2bf(hv.w);
    *(ushort4*)&hbr[o] = bv;
  }
  as_[u] = ss; ad_[u] = dd;
}

// ---------------- aggregation: single pass, no max-shift, bf16 h gather ----
// Softmax shift is mathematically redundant (alpha = e/sum e); logits here are
// lrelu(a_s+a_d) with a ~ N(0,1) so exp() is safe in fp32 (clamped at 80).

// Layer 1: H=4, O=32. bf16 row = 256 B = 32 lanes x ushort4. 2 edges/wave.
__global__ __launch_bounds__(256) void k_agg1(const int* __restrict__ rp, const int* __restrict__ csr,
    const float* __restrict__ as_, const float* __restrict__ ad_,
    const ushort4* __restrict__ hb, const float* __restrict__ bias,
    float* __restrict__ out, int N){
  int n = blockIdx.x*4 + (threadIdx.x>>6);
  if (n >= N) return;
  int lane = threadIdx.x & 63;
  int half = lane>>5, li = lane&31, head = li>>3;
  int start = rp[n], end = rp[n+1];
  float4 ad4 = *(const float4*)&ad_[n*4];
  float4 as4 = *(const float4*)&as_[n*4];
  float adh = sel4(ad4.x,ad4.y,ad4.z,ad4.w,head);
  float slh = lrelu(sel4(as4.x,as4.y,as4.z,as4.w,head) + adh);
  float a0=0.f,a1=0.f,a2=0.f,a3=0.f,l=0.f;
  for (int i=start+half; i<end; i+=2){
    int s = csr[i];
    float w = __expf(fminf(lrelu(as_[s*4+head] + adh), 80.f));
    ushort4 v = hb[(size_t)s*32 + li];
    a0 += w*bf2f(v.x); a1 += w*bf2f(v.y); a2 += w*bf2f(v.z); a3 += w*bf2f(v.w);
    if ((li&7)==0) l += w;
  }
  if (half == 0){
    float w = __expf(fminf(slh, 80.f));
    ushort4 v = hb[(size_t)n*32 + li];
    a0 += w*bf2f(v.x); a1 += w*bf2f(v.y); a2 += w*bf2f(v.z); a3 += w*bf2f(v.w);
    if ((li&7)==0) l += w;
  }
  a0 += __shfl_xor(a0,32); a1 += __shfl_xor(a1,32);
  a2 += __shfl_xor(a2,32); a3 += __shfl_xor(a3,32);
  l  += __shfl_xor(l,32);
  float lt = __shfl(l, (lane & 32) | (head<<3));  // total denom for this head
  if (half == 0){
    float invh = 1.f/lt;
    float4 bv = *(const float4*)&bias[li*4];
    float4 r;
    r.x = eluf(a0*invh + bv.x); r.y = eluf(a1*invh + bv.y);
    r.z = eluf(a2*invh + bv.z); r.w = eluf(a3*invh + bv.w);
    *(float4*)&out[n*128 + li*4] = r;
  }
}

// Layer 2: H=2, O=16. bf16 row = 64 B = 8 lanes x ushort4. 8 edges/wave.
__global__ __launch_bounds__(256) void k_agg2(const int* __restrict__ rp, const int* __restrict__ csr,
    const float* __restrict__ as_, const float* __restrict__ ad_,
    const ushort4* __restrict__ hb, const float* __restrict__ bias,
    float* __restrict__ out, int N){
  int n = blockIdx.x*4 + (threadIdx.x>>6);
  if (n >= N) return;
  int lane = threadIdx.x & 63;
  int grp = lane>>3, li = lane&7, head = li>>2;
  int start = rp[n], end = rp[n+1];
  float2 ad2 = *(const float2*)&ad_[n*2];
  float2 as2 = *(const float2*)&as_[n*2];
  float adh = sel2(ad2.x,ad2.y,head);
  float slh = lrelu(sel2(as2.x,as2.y,head) + adh);
  float a0=0.f,a1=0.f,a2=0.f,a3=0.f,l=0.f;
  for (int i=start+grp; i<end; i+=8){
    int s = csr[i];
    float w = __expf(fminf(lrelu(as_[s*2+head] + adh), 80.f));
    ushort4 v = hb[(size_t)s*8 + li];
    a0 += w*bf2f(v.x); a1 += w*bf2f(v.y); a2 += w*bf2f(v.z); a3 += w*bf2f(v.w);
    if ((li&3)==0) l += w;
  }
  if (grp == 0){
    float w = __expf(fminf(slh, 80.f));
    ushort4 v = hb[(size_t)n*8 + li];
    a0 += w*bf2f(v.x); a1 += w*bf2f(v.y); a2 += w*bf2f(v.z); a3 += w*bf2f(v.w);
    if ((li&3)==0) l += w;
  }
  #pragma unroll
  for (int msk=8; msk<64; msk<<=1){
    a0 += __shfl_xor(a0,msk); a1 += __shfl_xor(a1,msk);
    a2 += __shfl_xor(a2,msk); a3 += __shfl_xor(a3,msk);
    l  += __shfl_xor(l,msk);
  }
  float lt = __shfl(l, (lane & 56) | (head<<2));
  if (grp == 0){
    float invh = 1.f/lt;
    float4 bv = *(const float4*)&bias[li*4];
    float4 r;
    r.x = eluf(a0*invh + bv.x); r.y = eluf(a1*invh + bv.y);
    r.z = eluf(a2*invh + bv.z); r.w = eluf(a3*invh + bv.w);
    *(float4*)&out[n*32 + li*4] = r;
  }
}

// Layer 3: H=1, O=2 (fp32 h). One lane per edge; bias + log_softmax epilogue.
__global__ __launch_bounds__(256) void k_agg3(const int* __restrict__ rp, const int* __restrict__ csr,
    const float* __restrict__ as_, const float* __restrict__ ad_,
    const float* __restrict__ h, const float* __restrict__ bias,
    float* __restrict__ out, int N){
  int n = blockIdx.x*4 + (threadIdx.x>>6);
  if (n >= N) return;
  int lane = threadIdx.x & 63;
  int start = rp[n], end = rp[n+1];
  float adh = ad_[n];
  float sl = lrelu(as_[n] + adh);
  const float2* h2 = (const float2*)h;
  float l = 0.f;
  float2 acc = make_float2(0.f, 0.f);
  for (int i=start+lane; i<end; i+=64){
    int s = csr[i];
    float w = __expf(fminf(lrelu(as_[s] + adh), 80.f));
    l += w;
    float2 v = h2[s];
    acc.x += w*v.x; acc.y += w*v.y;
  }
  if (lane == 0){
    float w = __expf(fminf(sl, 80.f));
    l += w;
    float2 v = h2[n];
    acc.x += w*v.x; acc.y += w*v.y;
  }
  l = wred_sum(l);
  acc.x = wred_sum(acc.x); acc.y = wred_sum(acc.y);
  if (lane == 0){
    float inv = 1.f/l;
    float g0 = acc.x*inv + bias[0];
    float g1 = acc.y*inv + bias[1];
    float mm = fmaxf(g0, g1);
    float lse = mm + logf(__expf(g0-mm) + __expf(g1-mm));
    *(float2*)&out[2*n] = make_float2(g0-lse, g1-lse);
  }
}

// ---------------- launch ----------------
extern "C" void kernel_launch(void* const* d_in, const int* in_sizes, int n_in,
                              void* d_out, int out_size, void* d_ws, size_t ws_size,
                              hipStream_t stream) {
  const float* x   = (const float*)d_in[0];
  const void*  ei  = d_in[1];
  const float* W1  = (const float*)d_in[2];
  const float* as1 = (const float*)d_in[3];
  const float* ad1 = (const float*)d_in[4];
  const float* b1  = (const float*)d_in[5];
  const float* W2  = (const float*)d_in[6];
  const float* as2 = (const float*)d_in[7];
  const float* ad2 = (const float*)d_in[8];
  const float* b2  = (const float*)d_in[9];
  const float* W3  = (const float*)d_in[10];
  const float* as3 = (const float*)d_in[11];
  const float* ad3 = (const float*)d_in[12];
  const float* b3  = (const float*)d_in[13];

  int N = in_sizes[0] / 128;
  int E = in_sizes[1] / 2;

  char* w = (char*)d_ws;
  size_t off = 0;
  auto alloc = [&](size_t bytes)->void*{
    void* p = w + off; off += (bytes + 255) & ~(size_t)255; return p;
  };
  int*   flag   = (int*)alloc(256);
  int*   bsum   = (int*)alloc(4096);
  int*   cnt    = (int*)alloc((size_t)N*4);
  int*   rp     = (int*)alloc((size_t)(N+1)*4);
  int*   cur    = (int*)alloc((size_t)N*4);
  int*   csr    = (int*)alloc((size_t)E*4);
  float* as_buf = (float*)alloc((size_t)N*4*4);
  float* ad_buf = (float*)alloc((size_t)N*4*4);
  float* hbuf   = (float*)alloc((size_t)N*128*4);
  float* xbuf   = (float*)alloc((size_t)N*128*4);
  unsigned short* hb = (unsigned short*)alloc((size_t)N*128*2);
  if (off > ws_size) return;  // workspace too small -> visible failure

  hipMemsetAsync(cnt, 0, (size_t)N*4, stream);
  k_detect<<<1, 64, 0, stream>>>((const int*)ei, flag);
  int eb = (E + 255)/256;
  k_count<<<eb, 256, 0, stream>>>(ei, flag, cnt, E);
  int nb1 = (N + 1023)/1024;
  k_scan1<<<nb1, 256, 0, stream>>>(cnt, rp, bsum, N);
  k_scan2<<<1, 256, 0, stream>>>(bsum, nb1);
  k_scan3<<<(N + 255)/256, 256, 0, stream>>>(rp, cur, bsum, N, E);
  k_scatter<<<eb, 256, 0, stream>>>(ei, flag, cur, csr, E);

  // layer 1: Fin=128, H=4, O=32, concat, ELU
  k_gemm1<<<(N + 31)/32, 256, 0, stream>>>(x, W1, hbuf, N);
  k_att<4,32><<<(N*4 + 255)/256, 256, 0, stream>>>(hbuf, as1, ad1, as_buf, ad_buf, hb, N);
  k_agg1<<<(N + 3)/4, 256, 0, stream>>>(rp, csr, as_buf, ad_buf, (const ushort4*)hb, b1, xbuf, N);

  // layer 2: Fin=128, H=2, O=16, concat, ELU
  k_gemm2<<<(N + 63)/64, 128, 0, stream>>>(xbuf, W2, hbuf, N);
  k_att<2,16><<<(N*2 + 255)/256, 256, 0, stream>>>(hbuf, as2, ad2, as_buf, ad_buf, hb, N);
  k_agg2<<<(N + 3)/4, 256, 0, stream>>>(rp, csr, as_buf, ad_buf, (const ushort4*)hb, b2, xbuf, N);

  // layer 3: Fin=32, H=1, O=2, mean(=identity), bias + log_softmax
  k_gemm3<<<(N + 255)/256, 256, 0, stream>>>(xbuf, W3, as3, ad3, hbuf, as_buf, ad_buf, N);
  k_agg3<<<(N + 3)/4, 256, 0, stream>>>(rp, csr, as_buf, ad_buf, hbuf, b3, (float*)d_out, N);
}

// Round 3
// 488.652 us; speedup vs baseline: 1.3977x; 1.2961x over previous
//
#include <hip/hip_runtime.h>
#include <math.h>

// ---------------- helpers ----------------
static __device__ __forceinline__ float lrelu(float x){ return x > 0.f ? x : 0.2f*x; }
static __device__ __forceinline__ float eluf(float x){ return x > 0.f ? x : expm1f(x); }
static __device__ __forceinline__ float sel4(float a,float b,float c,float d,int i){
  float lo = (i&1)? b : a; float hi = (i&1)? d : c; return (i&2)? hi : lo;
}
static __device__ __forceinline__ float sel2(float a,float b,int i){ return (i&1)? b : a; }
static __device__ __forceinline__ float wred_sum(float v){
  v += __shfl_xor(v, 32); v += __shfl_xor(v, 16); v += __shfl_xor(v, 8);
  v += __shfl_xor(v, 4);  v += __shfl_xor(v, 2);  v += __shfl_xor(v, 1);
  return v;
}
static __device__ __forceinline__ unsigned short f2bf(float f){
  unsigned int u = __float_as_uint(f);
  unsigned int r = (u + 0x7FFFu + ((u>>16)&1u)) >> 16;   // round-nearest-even
  return (unsigned short)r;
}
static __device__ __forceinline__ float bf2f(unsigned short s){
  return __uint_as_float(((unsigned int)s)<<16);
}

// ---------------- edge decode + bucketed CSR build ----------------
// Bucket = dst>>7 (128 dst per bucket). Random 4B scatters are replaced by:
//   A) LDS-privatized bucket histogram
//   B) register-cached chunk scatter of packed (src | dloc<<25) into
//      cursor-ordered bucket regions (L2 lines fill completely)
//   C) per-bucket local CSR: all random writes confined to an ~8KB window.

__global__ void k_detect(const int* __restrict__ ei, int* __restrict__ flag){
  int lane = threadIdx.x;
  int w = ei[2*lane + 1];
  unsigned long long b = __ballot(w != 0);
  if (lane == 0) flag[0] = (b == 0ull) ? 1 : 0;   // 1 => int64
}

__global__ __launch_bounds__(256) void k_bhist(const void* __restrict__ ei,
    const int* __restrict__ flag, int* __restrict__ gbcnt, int E, int NB){
  extern __shared__ int lcnt[];
  for (int i=threadIdx.x; i<NB; i+=256) lcnt[i]=0;
  __syncthreads();
  bool is64 = flag[0] != 0;
  int stride = gridDim.x*256;
  for (int e = blockIdx.x*256 + threadIdx.x; e < E; e += stride){
    int d = is64 ? (int)((const long long*)ei)[(size_t)E+e]
                 : ((const int*)ei)[(size_t)E+e];
    atomicAdd(&lcnt[d>>7], 1);
  }
  __syncthreads();
  for (int i=threadIdx.x; i<NB; i+=256){
    int c = lcnt[i];
    if (c) atomicAdd(&gbcnt[i], c);
  }
}

// exclusive scan of gbcnt[NB] -> gbbase, gcursor (single block)
__global__ __launch_bounds__(256) void k_bscan(const int* __restrict__ gbcnt,
    int* __restrict__ gbbase, int* __restrict__ gcursor, int NB){
  __shared__ int sh[256];
  __shared__ int carry;
  int t = threadIdx.x;
  if (t==0) carry = 0;
  __syncthreads();
  for (int base=0; base<NB; base+=256){
    int idx = base+t;
    int v = (idx<NB)? gbcnt[idx] : 0;
    sh[t]=v; __syncthreads();
    for (int off=1; off<256; off<<=1){
      int add = (t>=off)? sh[t-off] : 0;
      __syncthreads();
      sh[t]+=add;
      __syncthreads();
    }
    int excl = sh[t]-v+carry;
    if (idx<NB){ gbbase[idx]=excl; gcursor[idx]=excl; }
    __syncthreads();
    if (t==0) carry += sh[255];
    __syncthreads();
  }
}

#define BS_ITEMS 16
__global__ __launch_bounds__(256) void k_bscatter(const void* __restrict__ ei,
    const int* __restrict__ flag, int* __restrict__ gcursor,
    unsigned int* __restrict__ ebuf, int E, int NB){
  extern __shared__ int lds[];     // lcnt[NB] then lbase[NB]
  int* lcnt = lds; int* lbase = lds + NB;
  for (int i=threadIdx.x; i<NB; i+=256) lcnt[i]=0;
  __syncthreads();
  bool is64 = flag[0] != 0;
  int base = blockIdx.x*(256*BS_ITEMS);
  unsigned int ent[BS_ITEMS]; int bk[BS_ITEMS];
  #pragma unroll
  for (int i=0;i<BS_ITEMS;i++){
    int e = base + i*256 + threadIdx.x;
    if (e < E){
      int s, d;
      if (is64){ const long long* p=(const long long*)ei; s=(int)p[e]; d=(int)p[(size_t)E+e]; }
      else     { const int* p=(const int*)ei;            s=p[e];      d=p[(size_t)E+e]; }
      int b = d>>7;
      bk[i] = b;
      ent[i] = (unsigned int)s | ((unsigned int)(d & 127) << 25);
      atomicAdd(&lcnt[b], 1);
    } else bk[i] = -1;
  }
  __syncthreads();
  for (int i=threadIdx.x; i<NB; i+=256){
    int c = lcnt[i];
    lbase[i] = c ? atomicAdd(&gcursor[i], c) : 0;
  }
  __syncthreads();
  for (int i=threadIdx.x; i<NB; i+=256) lcnt[i]=0;  // reuse as cursor
  __syncthreads();
  #pragma unroll
  for (int i=0;i<BS_ITEMS;i++){
    if (bk[i] >= 0){
      int pos = lbase[bk[i]] + atomicAdd(&lcnt[bk[i]], 1);
      ebuf[pos] = ent[i];
    }
  }
}

// one block per bucket: local histogram + scan -> rp, dst-ordered csr
__global__ __launch_bounds__(256) void k_bcsr(const unsigned int* __restrict__ ebuf,
    const int* __restrict__ gbbase, const int* __restrict__ gbcnt,
    int* __restrict__ rp, int* __restrict__ csr, int N, int NB, int E){
  __shared__ int lcnt[128];
  __shared__ int lexc[128];
  __shared__ int lcur[128];
  __shared__ int sc[256];
  int b = blockIdx.x, t = threadIdx.x;
  int d0 = b<<7;
  int R = N - d0; if (R > 128) R = 128;
  if (t < 128){ lcnt[t]=0; lcur[t]=0; }
  __syncthreads();
  int base = gbbase[b], cnt = gbcnt[b];
  for (int i=t; i<cnt; i+=256){
    unsigned int e = ebuf[base+i];
    atomicAdd(&lcnt[e>>25], 1);
  }
  __syncthreads();
  int v = (t<128)? lcnt[t] : 0;
  sc[t]=v; __syncthreads();
  for (int off=1; off<128; off<<=1){
    int add = (t>=off)? sc[t-off] : 0;
    __syncthreads();
    sc[t]+=add;
    __syncthreads();
  }
  if (t<128) lexc[t] = sc[t]-v;
  __syncthreads();
  if (t < R) rp[d0+t] = base + lexc[t];
  if (b == NB-1 && t == 0) rp[N] = E;
  for (int i=t; i<cnt; i+=256){
    unsigned int e = ebuf[base+i];
    int dl = e>>25;
    int pos = base + lexc[dl] + atomicAdd(&lcur[dl], 1);
    csr[pos] = (int)(e & 0x1FFFFFFu);
  }
}

// ---------------- GEMMs (h = x @ W), fp32 vector ALU ----------------
__global__ __launch_bounds__(256) void k_gemm1(const float* __restrict__ x,
                                               const float* __restrict__ W,
                                               float* __restrict__ h, int N){
  __shared__ float xs[32*128];
  int t = threadIdx.x;
  int r0 = blockIdx.x*32;
  {
    int row = t>>5, k4 = (t&31)*4;
    #pragma unroll
    for (int p=0;p<4;p++, row+=8){
      int gr = r0+row;
      float4 v = make_float4(0.f,0.f,0.f,0.f);
      if (gr < N) v = *(const float4*)&x[gr*128 + k4];
      *(float4*)&xs[row*128 + k4] = v;
    }
  }
  __syncthreads();
  int tc = (t&31)*4, tr = (t>>5)*4;
  float acc[4][4];
  #pragma unroll
  for (int i=0;i<4;i++){ acc[i][0]=0.f; acc[i][1]=0.f; acc[i][2]=0.f; acc[i][3]=0.f; }
  #pragma unroll 4
  for (int k=0;k<128;k++){
    float4 wv = *(const float4*)&W[k*128 + tc];
    #pragma unroll
    for (int i=0;i<4;i++){
      float xv = xs[(tr+i)*128 + k];
      acc[i][0] += xv*wv.x; acc[i][1] += xv*wv.y;
      acc[i][2] += xv*wv.z; acc[i][3] += xv*wv.w;
    }
  }
  #pragma unroll
  for (int i=0;i<4;i++){
    int gr = r0 + tr + i;
    if (gr < N)
      *(float4*)&h[gr*128 + tc] = make_float4(acc[i][0],acc[i][1],acc[i][2],acc[i][3]);
  }
}

#define G2PAD 132
__global__ __launch_bounds__(128) void k_gemm2(const float* __restrict__ x,
                                               const float* __restrict__ W,
                                               float* __restrict__ h, int N){
  __shared__ float xs[64*G2PAD];
  int t = threadIdx.x;
  int r0 = blockIdx.x*64;
  {
    int row = t>>5, k4 = (t&31)*4;
    #pragma unroll
    for (int p=0;p<16;p++, row+=4){
      int gr = r0+row;
      float4 v = make_float4(0.f,0.f,0.f,0.f);
      if (gr < N) v = *(const float4*)&x[gr*128 + k4];
      *(float4*)&xs[row*G2PAD + k4] = v;
    }
  }
  __syncthreads();
  int tc = (t&7)*4, tr = (t>>3)*4;
  float acc[4][4];
  #pragma unroll
  for (int i=0;i<4;i++){ acc[i][0]=0.f; acc[i][1]=0.f; acc[i][2]=0.f; acc[i][3]=0.f; }
  #pragma unroll 4
  for (int k=0;k<128;k++){
    float4 wv = *(const float4*)&W[k*32 + tc];
    #pragma unroll
    for (int i=0;i<4;i++){
      float xv = xs[(tr+i)*G2PAD + k];
      acc[i][0] += xv*wv.x; acc[i][1] += xv*wv.y;
      acc[i][2] += xv*wv.z; acc[i][3] += xv*wv.w;
    }
  }
  #pragma unroll
  for (int i=0;i<4;i++){
    int gr = r0 + tr + i;
    if (gr < N)
      *(float4*)&h[gr*32 + tc] = make_float4(acc[i][0],acc[i][1],acc[i][2],acc[i][3]);
  }
}

__global__ void k_gemm3(const float* __restrict__ x, const float* __restrict__ W,
                        const float* __restrict__ atts, const float* __restrict__ attd,
                        float* __restrict__ h, float* __restrict__ as_,
                        float* __restrict__ ad_, int N){
  int n = blockIdx.x*blockDim.x + threadIdx.x;
  if (n >= N) return;
  const float* xr = x + n*32;
  float a0 = 0.f, a1 = 0.f;
  #pragma unroll
  for (int k=0;k<32;k++){ float xv = xr[k]; a0 += xv*W[2*k]; a1 += xv*W[2*k+1]; }
  h[2*n] = a0; h[2*n+1] = a1;
  as_[n] = a0*atts[0] + a1*atts[1];
  ad_[n] = a0*attd[0] + a1*attd[1];
}

template<int H, int O>
__global__ void k_att(const float* __restrict__ h, const float* __restrict__ atts,
                      const float* __restrict__ attd, float* __restrict__ as_,
                      float* __restrict__ ad_, unsigned short* __restrict__ hb, int N){
  int u = blockIdx.x*blockDim.x + threadIdx.x;
  if (u >= N*H) return;
  int hh = u & (H-1);
  const float* hr = h + (size_t)u*O;
  unsigned short* hbr = hb + (size_t)u*O;
  const float* sa = atts + hh*O;
  const float* da = attd + hh*O;
  float ss = 0.f, dd = 0.f;
  #pragma unroll
  for (int o=0;o<O;o+=4){
    float4 hv = *(const float4*)&hr[o];
    float4 sv = *(const float4*)&sa[o];
    float4 dv = *(const float4*)&da[o];
    ss += hv.x*sv.x + hv.y*sv.y + hv.z*sv.z + hv.w*sv.w;
    dd += hv.x*dv.x + hv.y*dv.y + hv.z*dv.z + hv.w*dv.w;
    ushort4 bv;
    bv.x = f2bf(hv.x); bv.y = f2bf(hv.y); bv.z = f2bf(hv.z); bv.w = f2bf(hv.w);
    *(ushort4*)&hbr[o] = bv;
  }
  as_[u] = ss; ad_[u] = dd;
}

// ---------------- aggregation: single pass, no max-shift, bf16 h gather ----
__global__ __launch_bounds__(256) void k_agg1(const int* __restrict__ rp, const int* __restrict__ csr,
    const float* __restrict__ as_, const float* __restrict__ ad_,
    const ushort4* __restrict__ hb, const float* __restrict__ bias,
    float* __restrict__ out, int N){
  int n = blockIdx.x*4 + (threadIdx.x>>6);
  if (n >= N) return;
  int lane = threadIdx.x & 63;
  int half = lane>>5, li = lane&31, head = li>>3;
  int start = rp[n], end = rp[n+1];
  float4 ad4 = *(const float4*)&ad_[n*4];
  float4 as4 = *(const float4*)&as_[n*4];
  float adh = sel4(ad4.x,ad4.y,ad4.z,ad4.w,head);
  float slh = lrelu(sel4(as4.x,as4.y,as4.z,as4.w,head) + adh);
  float a0=0.f,a1=0.f,a2=0.f,a3=0.f,l=0.f;
  for (int i=start+half; i<end; i+=2){
    int s = csr[i];
    float w = __expf(fminf(lrelu(as_[s*4+head] + adh), 80.f));
    ushort4 v = hb[(size_t)s*32 + li];
    a0 += w*bf2f(v.x); a1 += w*bf2f(v.y); a2 += w*bf2f(v.z); a3 += w*bf2f(v.w);
    if ((li&7)==0) l += w;
  }
  if (half == 0){
    float w = __expf(fminf(slh, 80.f));
    ushort4 v = hb[(size_t)n*32 + li];
    a0 += w*bf2f(v.x); a1 += w*bf2f(v.y); a2 += w*bf2f(v.z); a3 += w*bf2f(v.w);
    if ((li&7)==0) l += w;
  }
  a0 += __shfl_xor(a0,32); a1 += __shfl_xor(a1,32);
  a2 += __shfl_xor(a2,32); a3 += __shfl_xor(a3,32);
  l  += __shfl_xor(l,32);
  float lt = __shfl(l, (lane & 32) | (head<<3));
  if (half == 0){
    float invh = 1.f/lt;
    float4 bv = *(const float4*)&bias[li*4];
    float4 r;
    r.x = eluf(a0*invh + bv.x); r.y = eluf(a1*invh + bv.y);
    r.z = eluf(a2*invh + bv.z); r.w = eluf(a3*invh + bv.w);
    *(float4*)&out[n*128 + li*4] = r;
  }
}

__global__ __launch_bounds__(256) void k_agg2(const int* __restrict__ rp, const int* __restrict__ csr,
    const float* __restrict__ as_, const float* __restrict__ ad_,
    const ushort4* __restrict__ hb, const float* __restrict__ bias,
    float* __restrict__ out, int N){
  int n = blockIdx.x*4 + (threadIdx.x>>6);
  if (n >= N) return;
  int lane = threadIdx.x & 63;
  int grp = lane>>3, li = lane&7, head = li>>2;
  int start = rp[n], end = rp[n+1];
  float2 ad2 = *(const float2*)&ad_[n*2];
  float2 as2 = *(const float2*)&as_[n*2];
  float adh = sel2(ad2.x,ad2.y,head);
  float slh = lrelu(sel2(as2.x,as2.y,head) + adh);
  float a0=0.f,a1=0.f,a2=0.f,a3=0.f,l=0.f;
  for (int i=start+grp; i<end; i+=8){
    int s = csr[i];
    float w = __expf(fminf(lrelu(as_[s*2+head] + adh), 80.f));
    ushort4 v = hb[(size_t)s*8 + li];
    a0 += w*bf2f(v.x); a1 += w*bf2f(v.y); a2 += w*bf2f(v.z); a3 += w*bf2f(v.w);
    if ((li&3)==0) l += w;
  }
  if (grp == 0){
    float w = __expf(fminf(slh, 80.f));
    ushort4 v = hb[(size_t)n*8 + li];
    a0 += w*bf2f(v.x); a1 += w*bf2f(v.y); a2 += w*bf2f(v.z); a3 += w*bf2f(v.w);
    if ((li&3)==0) l += w;
  }
  #pragma unroll
  for (int msk=8; msk<64; msk<<=1){
    a0 += __shfl_xor(a0,msk); a1 += __shfl_xor(a1,msk);
    a2 += __shfl_xor(a2,msk); a3 += __shfl_xor(a3,msk);
    l  += __shfl_xor(l,msk);
  }
  float lt = __shfl(l, (lane & 56) | (head<<2));
  if (grp == 0){
    float invh = 1.f/lt;
    float4 bv = *(const float4*)&bias[li*4];
    float4 r;
    r.x = eluf(a0*invh + bv.x); r.y = eluf(a1*invh + bv.y);
    r.z = eluf(a2*invh + bv.z); r.w = eluf(a3*invh + bv.w);
    *(float4*)&out[n*32 + li*4] = r;
  }
}

__global__ __launch_bounds__(256) void k_agg3(const int* __restrict__ rp, const int* __restrict__ csr,
    const float* __restrict__ as_, const float* __restrict__ ad_,
    const float* __restrict__ h, const float* __restrict__ bias,
    float* __restrict__ out, int N){
  int n = blockIdx.x*4 + (threadIdx.x>>6);
  if (n >= N) return;
  int lane = threadIdx.x & 63;
  int start = rp[n], end = rp[n+1];
  float adh = ad_[n];
  float sl = lrelu(as_[n] + adh);
  const float2* h2 = (const float2*)h;
  float l = 0.f;
  float2 acc = make_float2(0.f, 0.f);
  for (int i=start+lane; i<end; i+=64){
    int s = csr[i];
    float w = __expf(fminf(lrelu(as_[s] + adh), 80.f));
    l += w;
    float2 v = h2[s];
    acc.x += w*v.x; acc.y += w*v.y;
  }
  if (lane == 0){
    float w = __expf(fminf(sl, 80.f));
    l += w;
    float2 v = h2[n];
    acc.x += w*v.x; acc.y += w*v.y;
  }
  l = wred_sum(l);
  acc.x = wred_sum(acc.x); acc.y = wred_sum(acc.y);
  if (lane == 0){
    float inv = 1.f/l;
    float g0 = acc.x*inv + bias[0];
    float g1 = acc.y*inv + bias[1];
    float mm = fmaxf(g0, g1);
    float lse = mm + logf(__expf(g0-mm) + __expf(g1-mm));
    *(float2*)&out[2*n] = make_float2(g0-lse, g1-lse);
  }
}

// ---------------- launch ----------------
extern "C" void kernel_launch(void* const* d_in, const int* in_sizes, int n_in,
                              void* d_out, int out_size, void* d_ws, size_t ws_size,
                              hipStream_t stream) {
  const float* x   = (const float*)d_in[0];
  const void*  ei  = d_in[1];
  const float* W1  = (const float*)d_in[2];
  const float* as1 = (const float*)d_in[3];
  const float* ad1 = (const float*)d_in[4];
  const float* b1  = (const float*)d_in[5];
  const float* W2  = (const float*)d_in[6];
  const float* as2 = (const float*)d_in[7];
  const float* ad2 = (const float*)d_in[8];
  const float* b2  = (const float*)d_in[9];
  const float* W3  = (const float*)d_in[10];
  const float* as3 = (const float*)d_in[11];
  const float* ad3 = (const float*)d_in[12];
  const float* b3  = (const float*)d_in[13];

  int N = in_sizes[0] / 128;
  int E = in_sizes[1] / 2;
  int NB = (N + 127) >> 7;           // 128 dst per bucket

  char* w = (char*)d_ws;
  size_t off = 0;
  auto alloc = [&](size_t bytes)->void*{
    void* p = w + off; off += (bytes + 255) & ~(size_t)255; return p;
  };
  int*   flag    = (int*)alloc(256);
  int*   gbcnt   = (int*)alloc((size_t)NB*4);
  int*   gbbase  = (int*)alloc((size_t)NB*4);
  int*   gcursor = (int*)alloc((size_t)NB*4);
  int*   rp      = (int*)alloc((size_t)(N+1)*4);
  unsigned int* ebuf = (unsigned int*)alloc((size_t)E*4);
  int*   csr     = (int*)alloc((size_t)E*4);
  float* as_buf  = (float*)alloc((size_t)N*4*4);
  float* ad_buf  = (float*)alloc((size_t)N*4*4);
  float* hbuf    = (float*)alloc((size_t)N*128*4);
  float* xbuf    = (float*)alloc((size_t)N*128*4);
  unsigned short* hb = (unsigned short*)alloc((size_t)N*128*2);
  if (off > ws_size) return;  // workspace too small -> visible failure

  hipMemsetAsync(gbcnt, 0, (size_t)NB*4, stream);
  k_detect<<<1, 64, 0, stream>>>((const int*)ei, flag);
  k_bhist<<<256, 256, NB*4, stream>>>(ei, flag, gbcnt, E, NB);
  k_bscan<<<1, 256, 0, stream>>>(gbcnt, gbbase, gcursor, NB);
  int sb = (E + 256*BS_ITEMS - 1) / (256*BS_ITEMS);
  k_bscatter<<<sb, 256, 2*NB*4, stream>>>(ei, flag, gcursor, ebuf, E, NB);
  k_bcsr<<<NB, 256, 0, stream>>>(ebuf, gbbase, gbcnt, rp, csr, N, NB, E);

  // layer 1: Fin=128, H=4, O=32, concat, ELU
  k_gemm1<<<(N + 31)/32, 256, 0, stream>>>(x, W1, hbuf, N);
  k_att<4,32><<<(N*4 + 255)/256, 256, 0, stream>>>(hbuf, as1, ad1, as_buf, ad_buf, hb, N);
  k_agg1<<<(N + 3)/4, 256, 0, stream>>>(rp, csr, as_buf, ad_buf, (const ushort4*)hb, b1, xbuf, N);

  // layer 2: Fin=128, H=2, O=16, concat, ELU
  k_gemm2<<<(N + 63)/64, 128, 0, stream>>>(xbuf, W2, hbuf, N);
  k_att<2,16><<<(N*2 + 255)/256, 256, 0, stream>>>(hbuf, as2, ad2, as_buf, ad_buf, hb, N);
  k_agg2<<<(N + 3)/4, 256, 0, stream>>>(rp, csr, as_buf, ad_buf, (const ushort4*)hb, b2, xbuf, N);

  // layer 3: Fin=32, H=1, O=2, mean(=identity), bias + log_softmax
  k_gemm3<<<(N + 255)/256, 256, 0, stream>>>(xbuf, W3, as3, ad3, hbuf, as_buf, ad_buf, N);
  k_agg3<<<(N + 3)/4, 256, 0, stream>>>(rp, csr, as_buf, ad_buf, hbuf, b3, (float*)d_out, N);
}

// Round 4
// 437.922 us; speedup vs baseline: 1.5596x; 1.1158x over previous
//
#include <hip/hip_runtime.h>
#include <math.h>

// ---------------- helpers ----------------
static __device__ __forceinline__ float lrelu(float x){ return fmaxf(x, 0.2f*x); }
static __device__ __forceinline__ float eluf(float x){ return x > 0.f ? x : expm1f(x); }
static __device__ __forceinline__ float wred_sum(float v){
  v += __shfl_xor(v, 32); v += __shfl_xor(v, 16); v += __shfl_xor(v, 8);
  v += __shfl_xor(v, 4);  v += __shfl_xor(v, 2);  v += __shfl_xor(v, 1);
  return v;
}
static __device__ __forceinline__ unsigned short f2bf(float f){
  unsigned int u = __float_as_uint(f);
  unsigned int r = (u + 0x7FFFu + ((u>>16)&1u)) >> 16;   // round-nearest-even
  return (unsigned short)r;
}
static __device__ __forceinline__ float bflo(unsigned int u){ return __uint_as_float(u<<16); }
static __device__ __forceinline__ float bfhi(unsigned int u){ return __uint_as_float(u & 0xFFFF0000u); }

// ---------------- bucketed CSR build (bucket = dst>>7) ----------------
// int64-vs-int32 detect inlined: odd int32 words of an int64 edge list (node
// ids < 2^31) are all zero.
#define DETECT_IS64(ei_, s_is64_) \
  if (threadIdx.x < 64){ \
    int w_ = ((const int*)(ei_))[2*threadIdx.x + 1]; \
    unsigned long long b_ = __ballot(w_ != 0); \
    if (threadIdx.x == 0) s_is64_ = (b_ == 0ull); \
  } \
  __syncthreads();

__global__ __launch_bounds__(256) void k_bhist(const void* __restrict__ ei,
    int* __restrict__ gbcnt, int E, int NB){
  extern __shared__ int lcnt[];
  __shared__ int s_is64;
  for (int i=threadIdx.x; i<NB; i+=256) lcnt[i]=0;
  DETECT_IS64(ei, s_is64)
  int stride = gridDim.x*256;
  if (s_is64){
    const long long* p = (const long long*)ei;
    for (int e = blockIdx.x*256 + threadIdx.x; e < E; e += stride)
      atomicAdd(&lcnt[((int)p[(size_t)E+e])>>7], 1);
  } else {
    const int* p = (const int*)ei;
    for (int e = blockIdx.x*256 + threadIdx.x; e < E; e += stride)
      atomicAdd(&lcnt[p[(size_t)E+e]>>7], 1);
  }
  __syncthreads();
  for (int i=threadIdx.x; i<NB; i+=256){
    int c = lcnt[i];
    if (c) atomicAdd(&gbcnt[i], c);
  }
}

__global__ __launch_bounds__(256) void k_bscan(const int* __restrict__ gbcnt,
    int* __restrict__ gbbase, int* __restrict__ gcursor, int NB){
  __shared__ int sh[256];
  __shared__ int carry;
  int t = threadIdx.x;
  if (t==0) carry = 0;
  __syncthreads();
  for (int base=0; base<NB; base+=256){
    int idx = base+t;
    int v = (idx<NB)? gbcnt[idx] : 0;
    sh[t]=v; __syncthreads();
    for (int off=1; off<256; off<<=1){
      int add = (t>=off)? sh[t-off] : 0;
      __syncthreads();
      sh[t]+=add;
      __syncthreads();
    }
    int excl = sh[t]-v+carry;
    if (idx<NB){ gbbase[idx]=excl; gcursor[idx]=excl; }
    __syncthreads();
    if (t==0) carry += sh[255];
    __syncthreads();
  }
}

#define BS_ITEMS 16
__global__ __launch_bounds__(256) void k_bscatter(const void* __restrict__ ei,
    int* __restrict__ gcursor, unsigned int* __restrict__ ebuf, int E, int NB){
  extern __shared__ int lds[];     // lcnt[NB] then lbase[NB]
  __shared__ int s_is64;
  int* lcnt = lds; int* lbase = lds + NB;
  for (int i=threadIdx.x; i<NB; i+=256) lcnt[i]=0;
  DETECT_IS64(ei, s_is64)
  bool is64 = s_is64 != 0;
  int base = blockIdx.x*(256*BS_ITEMS);
  unsigned int ent[BS_ITEMS]; int bk[BS_ITEMS];
  #pragma unroll
  for (int i=0;i<BS_ITEMS;i++){
    int e = base + i*256 + threadIdx.x;
    if (e < E){
      int s, d;
      if (is64){ const long long* p=(const long long*)ei; s=(int)p[e]; d=(int)p[(size_t)E+e]; }
      else     { const int* p=(const int*)ei;            s=p[e];      d=p[(size_t)E+e]; }
      int b = d>>7;
      bk[i] = b;
      ent[i] = (unsigned int)s | ((unsigned int)(d & 127) << 25);
      atomicAdd(&lcnt[b], 1);
    } else bk[i] = -1;
  }
  __syncthreads();
  for (int i=threadIdx.x; i<NB; i+=256){
    int c = lcnt[i];
    lbase[i] = c ? atomicAdd(&gcursor[i], c) : 0;
  }
  __syncthreads();
  for (int i=threadIdx.x; i<NB; i+=256) lcnt[i]=0;  // reuse as cursor
  __syncthreads();
  #pragma unroll
  for (int i=0;i<BS_ITEMS;i++){
    if (bk[i] >= 0){
      int pos = lbase[bk[i]] + atomicAdd(&lcnt[bk[i]], 1);
      ebuf[pos] = ent[i];
    }
  }
}

__global__ __launch_bounds__(256) void k_bcsr(const unsigned int* __restrict__ ebuf,
    const int* __restrict__ gbbase, const int* __restrict__ gbcnt,
    int* __restrict__ rp, int* __restrict__ csr, int N, int NB, int E){
  __shared__ int lcnt[128];
  __shared__ int lexc[128];
  __shared__ int lcur[128];
  __shared__ int sc[256];
  int b = blockIdx.x, t = threadIdx.x;
  int d0 = b<<7;
  int R = N - d0; if (R > 128) R = 128;
  if (t < 128){ lcnt[t]=0; lcur[t]=0; }
  __syncthreads();
  int base = gbbase[b], cnt = gbcnt[b];
  for (int i=t; i<cnt; i+=256){
    unsigned int e = ebuf[base+i];
    atomicAdd(&lcnt[e>>25], 1);
  }
  __syncthreads();
  int v = (t<128)? lcnt[t] : 0;
  sc[t]=v; __syncthreads();
  for (int off=1; off<128; off<<=1){
    int add = (t>=off)? sc[t-off] : 0;
    __syncthreads();
    sc[t]+=add;
    __syncthreads();
  }
  if (t<128) lexc[t] = sc[t]-v;
  __syncthreads();
  if (t < R) rp[d0+t] = base + lexc[t];
  if (b == NB-1 && t == 0) rp[N] = E;
  for (int i=t; i<cnt; i+=256){
    unsigned int e = ebuf[base+i];
    int dl = e>>25;
    int pos = base + lexc[dl] + atomicAdd(&lcur[dl], 1);
    csr[pos] = (int)(e & 0x1FFFFFFu);
  }
}

// ---------------- GEMM 1: x(fp32,128) @ W1(128x128) -> hb (bf16) ----------
__global__ __launch_bounds__(256) void k_gemm1(const float* __restrict__ x,
                                               const float* __restrict__ W,
                                               unsigned short* __restrict__ hb, int N){
  __shared__ float xs[32*128];
  int t = threadIdx.x;
  int r0 = blockIdx.x*32;
  {
    int row = t>>5, k4 = (t&31)*4;
    #pragma unroll
    for (int p=0;p<4;p++, row+=8){
      int gr = r0+row;
      float4 v = make_float4(0.f,0.f,0.f,0.f);
      if (gr < N) v = *(const float4*)&x[gr*128 + k4];
      *(float4*)&xs[row*128 + k4] = v;
    }
  }
  __syncthreads();
  int tc = (t&31)*4, tr = (t>>5)*4;
  float acc[4][4];
  #pragma unroll
  for (int i=0;i<4;i++){ acc[i][0]=0.f; acc[i][1]=0.f; acc[i][2]=0.f; acc[i][3]=0.f; }
  #pragma unroll 4
  for (int k=0;k<128;k++){
    float4 wv = *(const float4*)&W[k*128 + tc];
    #pragma unroll
    for (int i=0;i<4;i++){
      float xv = xs[(tr+i)*128 + k];
      acc[i][0] += xv*wv.x; acc[i][1] += xv*wv.y;
      acc[i][2] += xv*wv.z; acc[i][3] += xv*wv.w;
    }
  }
  #pragma unroll
  for (int i=0;i<4;i++){
    int gr = r0 + tr + i;
    if (gr < N){
      ushort4 o;
      o.x = f2bf(acc[i][0]); o.y = f2bf(acc[i][1]);
      o.z = f2bf(acc[i][2]); o.w = f2bf(acc[i][3]);
      *(ushort4*)&hb[(size_t)gr*128 + tc] = o;
    }
  }
}

// ---------------- GEMM 2: xb(bf16,128) @ W2(128x32) -> hb2 (bf16) ---------
#define G2PAD 132
__global__ __launch_bounds__(128) void k_gemm2(const unsigned short* __restrict__ xb,
                                               const float* __restrict__ W,
                                               unsigned short* __restrict__ hb2, int N){
  __shared__ float xs[64*G2PAD];
  int t = threadIdx.x;
  int r0 = blockIdx.x*64;
  {
    const uint4* xb4 = (const uint4*)xb;   // row = 16 uint4
    int c = t&15, rr = t>>4;
    #pragma unroll
    for (int p=0;p<8;p++, rr+=8){
      int gr = r0+rr;
      uint4 v = make_uint4(0u,0u,0u,0u);
      if (gr < N) v = xb4[(size_t)gr*16 + c];
      float* dst = &xs[rr*G2PAD + c*8];
      dst[0]=bflo(v.x); dst[1]=bfhi(v.x); dst[2]=bflo(v.y); dst[3]=bfhi(v.y);
      dst[4]=bflo(v.z); dst[5]=bfhi(v.z); dst[6]=bflo(v.w); dst[7]=bfhi(v.w);
    }
  }
  __syncthreads();
  int tc = (t&7)*4, tr = (t>>3)*4;
  float acc[4][4];
  #pragma unroll
  for (int i=0;i<4;i++){ acc[i][0]=0.f; acc[i][1]=0.f; acc[i][2]=0.f; acc[i][3]=0.f; }
  #pragma unroll 4
  for (int k=0;k<128;k++){
    float4 wv = *(const float4*)&W[k*32 + tc];
    #pragma unroll
    for (int i=0;i<4;i++){
      float xv = xs[(tr+i)*G2PAD + k];
      acc[i][0] += xv*wv.x; acc[i][1] += xv*wv.y;
      acc[i][2] += xv*wv.z; acc[i][3] += xv*wv.w;
    }
  }
  #pragma unroll
  for (int i=0;i<4;i++){
    int gr = r0 + tr + i;
    if (gr < N){
      ushort4 o;
      o.x = f2bf(acc[i][0]); o.y = f2bf(acc[i][1]);
      o.z = f2bf(acc[i][2]); o.w = f2bf(acc[i][3]);
      *(ushort4*)&hb2[(size_t)gr*32 + tc] = o;
    }
  }
}

// ---------------- GEMM 3: x2b(bf16,32) @ W3(32x2) + att terms -------------
__global__ void k_gemm3(const unsigned short* __restrict__ x2b, const float* __restrict__ W,
                        const float* __restrict__ atts, const float* __restrict__ attd,
                        float* __restrict__ h, float* __restrict__ as_,
                        float* __restrict__ ad_, int N){
  int n = blockIdx.x*blockDim.x + threadIdx.x;
  if (n >= N) return;
  const uint4* xr = (const uint4*)(x2b + (size_t)n*32);
  float a0 = 0.f, a1 = 0.f;
  #pragma unroll
  for (int j=0;j<4;j++){
    uint4 v = xr[j];
    float xv[8] = { bflo(v.x),bfhi(v.x),bflo(v.y),bfhi(v.y),
                    bflo(v.z),bfhi(v.z),bflo(v.w),bfhi(v.w) };
    #pragma unroll
    for (int m=0;m<8;m++){
      int k = j*8+m;
      a0 += xv[m]*W[2*k]; a1 += xv[m]*W[2*k+1];
    }
  }
  h[2*n] = a0; h[2*n+1] = a1;
  as_[n] = a0*atts[0] + a1*atts[1];
  ad_[n] = a0*attd[0] + a1*attd[1];
}

// --------- attention terms from bf16 h: one thread per (node,head) --------
template<int H, int O>
__global__ void k_attb(const unsigned short* __restrict__ hb,
                       const float* __restrict__ atts, const float* __restrict__ attd,
                       float* __restrict__ as_, float* __restrict__ ad_, int N){
  int u = blockIdx.x*blockDim.x + threadIdx.x;
  if (u >= N*H) return;
  int hh = u & (H-1);
  const uint4* hr = (const uint4*)(hb + (size_t)u*O);
  const float* sa = atts + hh*O;
  const float* da = attd + hh*O;
  float ss = 0.f, dd = 0.f;
  #pragma unroll
  for (int j=0;j<O/8;j++){
    uint4 v = hr[j];
    float hv[8] = { bflo(v.x),bfhi(v.x),bflo(v.y),bfhi(v.y),
                    bflo(v.z),bfhi(v.z),bflo(v.w),bfhi(v.w) };
    #pragma unroll
    for (int m=0;m<8;m++){
      ss += hv[m]*sa[j*8+m]; dd += hv[m]*da[j*8+m];
    }
  }
  as_[u] = ss; ad_[u] = dd;
}

// ---------------- aggregation: single pass, 16B/lane gathers --------------
// No max-shift (softmax shift is redundant; logits ~O(10), exp clamped at 80).
// Denominator trick: all lanes in a head-group compute identical w, so an
// unconditional l+=w and cross-group xor-reduce leaves each lane holding the
// denominator for its own head.

// Layer 1: H=4,O=32. row=128 bf16=256B=16 lanes x uint4. 4 edges in flight.
__global__ __launch_bounds__(256) void k_agg1(const int* __restrict__ rp, const int* __restrict__ csr,
    const float* __restrict__ as_, const float* __restrict__ ad_,
    const uint4* __restrict__ hb4, const float* __restrict__ bias,
    unsigned short* __restrict__ outb, int N){
  int n = blockIdx.x*4 + (threadIdx.x>>6);
  if (n >= N) return;
  int lane = threadIdx.x & 63;
  int grp = lane>>4, li = lane&15, head = li>>2;
  int start = rp[n], end = rp[n+1];
  float adh = ad_[n*4+head];
  float slh = lrelu(as_[n*4+head] + adh);
  float a[8];
  #pragma unroll
  for (int k=0;k<8;k++) a[k]=0.f;
  float l = 0.f;
  for (int i=start+grp; i<end; i+=4){
    int s = csr[i];
    float w = __expf(fminf(lrelu(as_[s*4+head]+adh), 80.f));
    uint4 v = hb4[(size_t)s*16 + li];
    a[0]+=w*bflo(v.x); a[1]+=w*bfhi(v.x); a[2]+=w*bflo(v.y); a[3]+=w*bfhi(v.y);
    a[4]+=w*bflo(v.z); a[5]+=w*bfhi(v.z); a[6]+=w*bflo(v.w); a[7]+=w*bfhi(v.w);
    l += w;
  }
  if (grp == 0){
    float w = __expf(fminf(slh, 80.f));
    uint4 v = hb4[(size_t)n*16 + li];
    a[0]+=w*bflo(v.x); a[1]+=w*bfhi(v.x); a[2]+=w*bflo(v.y); a[3]+=w*bfhi(v.y);
    a[4]+=w*bflo(v.z); a[5]+=w*bfhi(v.z); a[6]+=w*bflo(v.w); a[7]+=w*bfhi(v.w);
    l += w;
  }
  #pragma unroll
  for (int msk=16; msk<64; msk<<=1){
    #pragma unroll
    for (int k=0;k<8;k++) a[k] += __shfl_xor(a[k], msk);
    l += __shfl_xor(l, msk);
  }
  if (grp == 0){
    float invh = 1.f/l;
    float4 b0 = *(const float4*)&bias[li*8];
    float4 b1 = *(const float4*)&bias[li*8+4];
    union { unsigned short us[8]; uint4 v; } pk;
    pk.us[0]=f2bf(eluf(a[0]*invh+b0.x)); pk.us[1]=f2bf(eluf(a[1]*invh+b0.y));
    pk.us[2]=f2bf(eluf(a[2]*invh+b0.z)); pk.us[3]=f2bf(eluf(a[3]*invh+b0.w));
    pk.us[4]=f2bf(eluf(a[4]*invh+b1.x)); pk.us[5]=f2bf(eluf(a[5]*invh+b1.y));
    pk.us[6]=f2bf(eluf(a[6]*invh+b1.z)); pk.us[7]=f2bf(eluf(a[7]*invh+b1.w));
    *(uint4*)&outb[(size_t)n*128 + li*8] = pk.v;
  }
}

// Layer 2: H=2,O=16. row=32 bf16=64B=4 lanes x uint4. 16 edges in flight.
__global__ __launch_bounds__(256) void k_agg2(const int* __restrict__ rp, const int* __restrict__ csr,
    const float* __restrict__ as_, const float* __restrict__ ad_,
    const uint4* __restrict__ hb4, const float* __restrict__ bias,
    unsigned short* __restrict__ outb, int N){
  int n = blockIdx.x*4 + (threadIdx.x>>6);
  if (n >= N) return;
  int lane = threadIdx.x & 63;
  int grp = lane>>2, li = lane&3, head = li>>1;
  int start = rp[n], end = rp[n+1];
  float adh = ad_[n*2+head];
  float slh = lrelu(as_[n*2+head] + adh);
  float a[8];
  #pragma unroll
  for (int k=0;k<8;k++) a[k]=0.f;
  float l = 0.f;
  for (int i=start+grp; i<end; i+=16){
    int s = csr[i];
    float w = __expf(fminf(lrelu(as_[s*2+head]+adh), 80.f));
    uint4 v = hb4[(size_t)s*4 + li];
    a[0]+=w*bflo(v.x); a[1]+=w*bfhi(v.x); a[2]+=w*bflo(v.y); a[3]+=w*bfhi(v.y);
    a[4]+=w*bflo(v.z); a[5]+=w*bfhi(v.z); a[6]+=w*bflo(v.w); a[7]+=w*bfhi(v.w);
    l += w;
  }
  if (grp == 0){
    float w = __expf(fminf(slh, 80.f));
    uint4 v = hb4[(size_t)n*4 + li];
    a[0]+=w*bflo(v.x); a[1]+=w*bfhi(v.x); a[2]+=w*bflo(v.y); a[3]+=w*bfhi(v.y);
    a[4]+=w*bflo(v.z); a[5]+=w*bfhi(v.z); a[6]+=w*bflo(v.w); a[7]+=w*bfhi(v.w);
    l += w;
  }
  #pragma unroll
  for (int msk=4; msk<64; msk<<=1){
    #pragma unroll
    for (int k=0;k<8;k++) a[k] += __shfl_xor(a[k], msk);
    l += __shfl_xor(l, msk);
  }
  if (grp == 0){
    float invh = 1.f/l;
    float4 b0 = *(const float4*)&bias[li*8];
    float4 b1 = *(const float4*)&bias[li*8+4];
    union { unsigned short us[8]; uint4 v; } pk;
    pk.us[0]=f2bf(eluf(a[0]*invh+b0.x)); pk.us[1]=f2bf(eluf(a[1]*invh+b0.y));
    pk.us[2]=f2bf(eluf(a[2]*invh+b0.z)); pk.us[3]=f2bf(eluf(a[3]*invh+b0.w));
    pk.us[4]=f2bf(eluf(a[4]*invh+b1.x)); pk.us[5]=f2bf(eluf(a[5]*invh+b1.y));
    pk.us[6]=f2bf(eluf(a[6]*invh+b1.z)); pk.us[7]=f2bf(eluf(a[7]*invh+b1.w));
    *(uint4*)&outb[(size_t)n*32 + li*8] = pk.v;
  }
}

// Layer 3: H=1, O=2 (fp32 h). One lane per edge; bias + log_softmax epilogue.
__global__ __launch_bounds__(256) void k_agg3(const int* __restrict__ rp, const int* __restrict__ csr,
    const float* __restrict__ as_, const float* __restrict__ ad_,
    const float* __restrict__ h, const float* __restrict__ bias,
    float* __restrict__ out, int N){
  int n = blockIdx.x*4 + (threadIdx.x>>6);
  if (n >= N) return;
  int lane = threadIdx.x & 63;
  int start = rp[n], end = rp[n+1];
  float adh = ad_[n];
  float sl = lrelu(as_[n] + adh);
  const float2* h2 = (const float2*)h;
  float l = 0.f;
  float2 acc = make_float2(0.f, 0.f);
  for (int i=start+lane; i<end; i+=64){
    int s = csr[i];
    float w = __expf(fminf(lrelu(as_[s] + adh), 80.f));
    l += w;
    float2 v = h2[s];
    acc.x += w*v.x; acc.y += w*v.y;
  }
  if (lane == 0){
    float w = __expf(fminf(sl, 80.f));
    l += w;
    float2 v = h2[n];
    acc.x += w*v.x; acc.y += w*v.y;
  }
  l = wred_sum(l);
  acc.x = wred_sum(acc.x); acc.y = wred_sum(acc.y);
  if (lane == 0){
    float inv = 1.f/l;
    float g0 = acc.x*inv + bias[0];
    float g1 = acc.y*inv + bias[1];
    float mm = fmaxf(g0, g1);
    float lse = mm + logf(__expf(g0-mm) + __expf(g1-mm));
    *(float2*)&out[2*n] = make_float2(g0-lse, g1-lse);
  }
}

// ---------------- launch ----------------
extern "C" void kernel_launch(void* const* d_in, const int* in_sizes, int n_in,
                              void* d_out, int out_size, void* d_ws, size_t ws_size,
                              hipStream_t stream) {
  const float* x   = (const float*)d_in[0];
  const void*  ei  = d_in[1];
  const float* W1  = (const float*)d_in[2];
  const float* as1 = (const float*)d_in[3];
  const float* ad1 = (const float*)d_in[4];
  const float* b1  = (const float*)d_in[5];
  const float* W2  = (const float*)d_in[6];
  const float* as2 = (const float*)d_in[7];
  const float* ad2 = (const float*)d_in[8];
  const float* b2  = (const float*)d_in[9];
  const float* W3  = (const float*)d_in[10];
  const float* as3 = (const float*)d_in[11];
  const float* ad3 = (const float*)d_in[12];
  const float* b3  = (const float*)d_in[13];

  int N = in_sizes[0] / 128;
  int E = in_sizes[1] / 2;
  int NB = (N + 127) >> 7;           // 128 dst per bucket

  char* w = (char*)d_ws;
  size_t off = 0;
  auto alloc = [&](size_t bytes)->void*{
    void* p = w + off; off += (bytes + 255) & ~(size_t)255; return p;
  };
  int*   gbcnt   = (int*)alloc((size_t)NB*4);
  int*   gbbase  = (int*)alloc((size_t)NB*4);
  int*   gcursor = (int*)alloc((size_t)NB*4);
  int*   rp      = (int*)alloc((size_t)(N+1)*4);
  unsigned int* ebuf = (unsigned int*)alloc((size_t)E*4);
  int*   csr     = (int*)alloc((size_t)E*4);
  float* as_buf  = (float*)alloc((size_t)N*4*4);
  float* ad_buf  = (float*)alloc((size_t)N*4*4);
  unsigned short* hb  = (unsigned short*)alloc((size_t)N*128*2); // layer1 h bf16
  unsigned short* xb  = (unsigned short*)alloc((size_t)N*128*2); // layer1 out bf16
  unsigned short* hb2 = (unsigned short*)alloc((size_t)N*32*2);  // layer2 h bf16
  unsigned short* x2b = (unsigned short*)alloc((size_t)N*32*2);  // layer2 out bf16
  float* h3      = (float*)alloc((size_t)N*2*4);                 // layer3 h fp32
  if (off > ws_size) return;  // workspace too small -> visible failure

  hipMemsetAsync(gbcnt, 0, (size_t)NB*4, stream);
  k_bhist<<<256, 256, NB*4, stream>>>(ei, gbcnt, E, NB);
  k_bscan<<<1, 256, 0, stream>>>(gbcnt, gbbase, gcursor, NB);
  int sb = (E + 256*BS_ITEMS - 1) / (256*BS_ITEMS);
  k_bscatter<<<sb, 256, 2*NB*4, stream>>>(ei, gcursor, ebuf, E, NB);
  k_bcsr<<<NB, 256, 0, stream>>>(ebuf, gbbase, gbcnt, rp, csr, N, NB, E);

  // layer 1: Fin=128, H=4, O=32, concat, ELU
  k_gemm1<<<(N + 31)/32, 256, 0, stream>>>(x, W1, hb, N);
  k_attb<4,32><<<(N*4 + 255)/256, 256, 0, stream>>>(hb, as1, ad1, as_buf, ad_buf, N);
  k_agg1<<<(N + 3)/4, 256, 0, stream>>>(rp, csr, as_buf, ad_buf, (const uint4*)hb, b1, xb, N);

  // layer 2: Fin=128, H=2, O=16, concat, ELU
  k_gemm2<<<(N + 63)/64, 128, 0, stream>>>(xb, W2, hb2, N);
  k_attb<2,16><<<(N*2 + 255)/256, 256, 0, stream>>>(hb2, as2, ad2, as_buf, ad_buf, N);
  k_agg2<<<(N + 3)/4, 256, 0, stream>>>(rp, csr, as_buf, ad_buf, (const uint4*)hb2, b2, x2b, N);

  // layer 3: Fin=32, H=1, O=2, mean(=identity), bias + log_softmax
  k_gemm3<<<(N + 255)/256, 256, 0, stream>>>(x2b, W3, as3, ad3, h3, as_buf, ad_buf, N);
  k_agg3<<<(N + 3)/4, 256, 0, stream>>>(rp, csr, as_buf, ad_buf, h3, b3, (float*)d_out, N);
}

// Round 5
// 430.231 us; speedup vs baseline: 1.5874x; 1.0179x over previous
//
#include <hip/hip_runtime.h>
#include <math.h>

// ---------------- helpers ----------------
static __device__ __forceinline__ float lrelu(float x){ return fmaxf(x, 0.2f*x); }
// fast ELU: expm1f is a branchy libm call; __expf(x)-1 differs by ~1ulp(1)=1e-7
static __device__ __forceinline__ float eluf(float x){ return x > 0.f ? x : __expf(x)-1.f; }
static __device__ __forceinline__ float wred_sum(float v){
  v += __shfl_xor(v, 32); v += __shfl_xor(v, 16); v += __shfl_xor(v, 8);
  v += __shfl_xor(v, 4);  v += __shfl_xor(v, 2);  v += __shfl_xor(v, 1);
  return v;
}
static __device__ __forceinline__ unsigned short f2bf(float f){
  unsigned int u = __float_as_uint(f);
  unsigned int r = (u + 0x7FFFu + ((u>>16)&1u)) >> 16;   // round-nearest-even
  return (unsigned short)r;
}
static __device__ __forceinline__ float bflo(unsigned int u){ return __uint_as_float(u<<16); }
static __device__ __forceinline__ float bfhi(unsigned int u){ return __uint_as_float(u & 0xFFFF0000u); }

// ---------------- bucketed CSR build (bucket = dst>>7) ----------------
#define DETECT_IS64(ei_, s_is64_) \
  if (threadIdx.x < 64){ \
    int w_ = ((const int*)(ei_))[2*threadIdx.x + 1]; \
    unsigned long long b_ = __ballot(w_ != 0); \
    if (threadIdx.x == 0) s_is64_ = (b_ == 0ull); \
  } \
  __syncthreads();

__global__ __launch_bounds__(256) void k_bhist(const void* __restrict__ ei,
    int* __restrict__ gbcnt, int E, int NB){
  extern __shared__ int lcnt[];
  __shared__ int s_is64;
  for (int i=threadIdx.x; i<NB; i+=256) lcnt[i]=0;
  DETECT_IS64(ei, s_is64)
  int stride = gridDim.x*256;
  if (s_is64){
    const long long* p = (const long long*)ei;
    for (int e = blockIdx.x*256 + threadIdx.x; e < E; e += stride)
      atomicAdd(&lcnt[((int)p[(size_t)E+e])>>7], 1);
  } else {
    const int* p = (const int*)ei;
    for (int e = blockIdx.x*256 + threadIdx.x; e < E; e += stride)
      atomicAdd(&lcnt[p[(size_t)E+e]>>7], 1);
  }
  __syncthreads();
  for (int i=threadIdx.x; i<NB; i+=256){
    int c = lcnt[i];
    if (c) atomicAdd(&gbcnt[i], c);
  }
}

__global__ __launch_bounds__(256) void k_bscan(const int* __restrict__ gbcnt,
    int* __restrict__ gbbase, int* __restrict__ gcursor, int NB){
  __shared__ int sh[256];
  __shared__ int carry;
  int t = threadIdx.x;
  if (t==0) carry = 0;
  __syncthreads();
  for (int base=0; base<NB; base+=256){
    int idx = base+t;
    int v = (idx<NB)? gbcnt[idx] : 0;
    sh[t]=v; __syncthreads();
    for (int off=1; off<256; off<<=1){
      int add = (t>=off)? sh[t-off] : 0;
      __syncthreads();
      sh[t]+=add;
      __syncthreads();
    }
    int excl = sh[t]-v+carry;
    if (idx<NB){ gbbase[idx]=excl; gcursor[idx]=excl; }
    __syncthreads();
    if (t==0) carry += sh[255];
    __syncthreads();
  }
}

#define BS_ITEMS 16
__global__ __launch_bounds__(256) void k_bscatter(const void* __restrict__ ei,
    int* __restrict__ gcursor, unsigned int* __restrict__ ebuf, int E, int NB){
  extern __shared__ int lds[];     // lcnt[NB] then lbase[NB]
  __shared__ int s_is64;
  int* lcnt = lds; int* lbase = lds + NB;
  for (int i=threadIdx.x; i<NB; i+=256) lcnt[i]=0;
  DETECT_IS64(ei, s_is64)
  bool is64 = s_is64 != 0;
  int base = blockIdx.x*(256*BS_ITEMS);
  unsigned int ent[BS_ITEMS]; int bk[BS_ITEMS];
  #pragma unroll
  for (int i=0;i<BS_ITEMS;i++){
    int e = base + i*256 + threadIdx.x;
    if (e < E){
      int s, d;
      if (is64){ const long long* p=(const long long*)ei; s=(int)p[e]; d=(int)p[(size_t)E+e]; }
      else     { const int* p=(const int*)ei;            s=p[e];      d=p[(size_t)E+e]; }
      int b = d>>7;
      bk[i] = b;
      ent[i] = (unsigned int)s | ((unsigned int)(d & 127) << 25);
      atomicAdd(&lcnt[b], 1);
    } else bk[i] = -1;
  }
  __syncthreads();
  for (int i=threadIdx.x; i<NB; i+=256){
    int c = lcnt[i];
    lbase[i] = c ? atomicAdd(&gcursor[i], c) : 0;
  }
  __syncthreads();
  for (int i=threadIdx.x; i<NB; i+=256) lcnt[i]=0;  // reuse as cursor
  __syncthreads();
  #pragma unroll
  for (int i=0;i<BS_ITEMS;i++){
    if (bk[i] >= 0){
      int pos = lbase[bk[i]] + atomicAdd(&lcnt[bk[i]], 1);
      ebuf[pos] = ent[i];
    }
  }
}

__global__ __launch_bounds__(256) void k_bcsr(const unsigned int* __restrict__ ebuf,
    const int* __restrict__ gbbase, const int* __restrict__ gbcnt,
    int* __restrict__ rp, int* __restrict__ csr, int N, int NB, int E){
  __shared__ int lcnt[128];
  __shared__ int lexc[128];
  __shared__ int lcur[128];
  __shared__ int sc[256];
  int b = blockIdx.x, t = threadIdx.x;
  int d0 = b<<7;
  int R = N - d0; if (R > 128) R = 128;
  if (t < 128){ lcnt[t]=0; lcur[t]=0; }
  __syncthreads();
  int base = gbbase[b], cnt = gbcnt[b];
  for (int i=t; i<cnt; i+=256){
    unsigned int e = ebuf[base+i];
    atomicAdd(&lcnt[e>>25], 1);
  }
  __syncthreads();
  int v = (t<128)? lcnt[t] : 0;
  sc[t]=v; __syncthreads();
  for (int off=1; off<128; off<<=1){
    int add = (t>=off)? sc[t-off] : 0;
    __syncthreads();
    sc[t]+=add;
    __syncthreads();
  }
  if (t<128) lexc[t] = sc[t]-v;
  __syncthreads();
  if (t < R) rp[d0+t] = base + lexc[t];
  if (b == NB-1 && t == 0) rp[N] = E;
  for (int i=t; i<cnt; i+=256){
    unsigned int e = ebuf[base+i];
    int dl = e>>25;
    int pos = base + lexc[dl] + atomicAdd(&lcur[dl], 1);
    csr[pos] = (int)(e & 0x1FFFFFFu);
  }
}

// ---------------- GEMM 1: x(fp32,128) @ W1(128x128) -> hb (bf16) ----------
__global__ __launch_bounds__(256) void k_gemm1(const float* __restrict__ x,
                                               const float* __restrict__ W,
                                               unsigned short* __restrict__ hb, int N){
  __shared__ float xs[32*128];
  int t = threadIdx.x;
  int r0 = blockIdx.x*32;
  {
    int row = t>>5, k4 = (t&31)*4;
    #pragma unroll
    for (int p=0;p<4;p++, row+=8){
      int gr = r0+row;
      float4 v = make_float4(0.f,0.f,0.f,0.f);
      if (gr < N) v = *(const float4*)&x[gr*128 + k4];
      *(float4*)&xs[row*128 + k4] = v;
    }
  }
  __syncthreads();
  int tc = (t&31)*4, tr = (t>>5)*4;
  float acc[4][4];
  #pragma unroll
  for (int i=0;i<4;i++){ acc[i][0]=0.f; acc[i][1]=0.f; acc[i][2]=0.f; acc[i][3]=0.f; }
  #pragma unroll 4
  for (int k=0;k<128;k++){
    float4 wv = *(const float4*)&W[k*128 + tc];
    #pragma unroll
    for (int i=0;i<4;i++){
      float xv = xs[(tr+i)*128 + k];
      acc[i][0] += xv*wv.x; acc[i][1] += xv*wv.y;
      acc[i][2] += xv*wv.z; acc[i][3] += xv*wv.w;
    }
  }
  #pragma unroll
  for (int i=0;i<4;i++){
    int gr = r0 + tr + i;
    if (gr < N){
      ushort4 o;
      o.x = f2bf(acc[i][0]); o.y = f2bf(acc[i][1]);
      o.z = f2bf(acc[i][2]); o.w = f2bf(acc[i][3]);
      *(ushort4*)&hb[(size_t)gr*128 + tc] = o;
    }
  }
}

// ---------------- GEMM 2: xb(bf16,128) @ W2(128x32) -> hb2 (bf16) ---------
#define G2PAD 132
__global__ __launch_bounds__(128) void k_gemm2(const unsigned short* __restrict__ xb,
                                               const float* __restrict__ W,
                                               unsigned short* __restrict__ hb2, int N){
  __shared__ float xs[64*G2PAD];
  int t = threadIdx.x;
  int r0 = blockIdx.x*64;
  {
    const uint4* xb4 = (const uint4*)xb;   // row = 16 uint4
    int c = t&15, rr = t>>4;
    #pragma unroll
    for (int p=0;p<8;p++, rr+=8){
      int gr = r0+rr;
      uint4 v = make_uint4(0u,0u,0u,0u);
      if (gr < N) v = xb4[(size_t)gr*16 + c];
      float* dst = &xs[rr*G2PAD + c*8];
      dst[0]=bflo(v.x); dst[1]=bfhi(v.x); dst[2]=bflo(v.y); dst[3]=bfhi(v.y);
      dst[4]=bflo(v.z); dst[5]=bfhi(v.z); dst[6]=bflo(v.w); dst[7]=bfhi(v.w);
    }
  }
  __syncthreads();
  int tc = (t&7)*4, tr = (t>>3)*4;
  float acc[4][4];
  #pragma unroll
  for (int i=0;i<4;i++){ acc[i][0]=0.f; acc[i][1]=0.f; acc[i][2]=0.f; acc[i][3]=0.f; }
  #pragma unroll 4
  for (int k=0;k<128;k++){
    float4 wv = *(const float4*)&W[k*32 + tc];
    #pragma unroll
    for (int i=0;i<4;i++){
      float xv = xs[(tr+i)*G2PAD + k];
      acc[i][0] += xv*wv.x; acc[i][1] += xv*wv.y;
      acc[i][2] += xv*wv.z; acc[i][3] += xv*wv.w;
    }
  }
  #pragma unroll
  for (int i=0;i<4;i++){
    int gr = r0 + tr + i;
    if (gr < N){
      ushort4 o;
      o.x = f2bf(acc[i][0]); o.y = f2bf(acc[i][1]);
      o.z = f2bf(acc[i][2]); o.w = f2bf(acc[i][3]);
      *(ushort4*)&hb2[(size_t)gr*32 + tc] = o;
    }
  }
}

// ---------------- GEMM 3: x2b(bf16,32) @ W3(32x2) + att terms -------------
__global__ void k_gemm3(const unsigned short* __restrict__ x2b, const float* __restrict__ W,
                        const float* __restrict__ atts, const float* __restrict__ attd,
                        float* __restrict__ h, float* __restrict__ as_,
                        float* __restrict__ ad_, int N){
  int n = blockIdx.x*blockDim.x + threadIdx.x;
  if (n >= N) return;
  const uint4* xr = (const uint4*)(x2b + (size_t)n*32);
  float a0 = 0.f, a1 = 0.f;
  #pragma unroll
  for (int j=0;j<4;j++){
    uint4 v = xr[j];
    float xv[8] = { bflo(v.x),bfhi(v.x),bflo(v.y),bfhi(v.y),
                    bflo(v.z),bfhi(v.z),bflo(v.w),bfhi(v.w) };
    #pragma unroll
    for (int m=0;m<8;m++){
      int k = j*8+m;
      a0 += xv[m]*W[2*k]; a1 += xv[m]*W[2*k+1];
    }
  }
  h[2*n] = a0; h[2*n+1] = a1;
  as_[n] = a0*atts[0] + a1*atts[1];
  ad_[n] = a0*attd[0] + a1*attd[1];
}

// --------- attention terms from bf16 h: one thread per (node,head) --------
template<int H, int O>
__global__ void k_attb(const unsigned short* __restrict__ hb,
                       const float* __restrict__ atts, const float* __restrict__ attd,
                       float* __restrict__ as_, float* __restrict__ ad_, int N){
  int u = blockIdx.x*blockDim.x + threadIdx.x;
  if (u >= N*H) return;
  int hh = u & (H-1);
  const uint4* hr = (const uint4*)(hb + (size_t)u*O);
  const float* sa = atts + hh*O;
  const float* da = attd + hh*O;
  float ss = 0.f, dd = 0.f;
  #pragma unroll
  for (int j=0;j<O/8;j++){
    uint4 v = hr[j];
    float hv[8] = { bflo(v.x),bfhi(v.x),bflo(v.y),bfhi(v.y),
                    bflo(v.z),bfhi(v.z),bflo(v.w),bfhi(v.w) };
    #pragma unroll
    for (int m=0;m<8;m++){
      ss += hv[m]*sa[j*8+m]; dd += hv[m]*da[j*8+m];
    }
  }
  as_[u] = ss; ad_[u] = dd;
}

// ---------------- aggregation: single pass, exp-deduplicated --------------
// Exp dedup: per 16-edge block, each of the 64 lanes computes exactly ONE
// (edge,head) weight (was: 16 redundant exps/edge). The gather sub-rounds
// fetch w/src via ds_bpermute (LDS pipe - off the saturated VALU). The
// denominator is an exact per-lane accumulation + xor-reduce.
// No max-shift (softmax shift is redundant; logits O(10), exp clamped at 80).

// Layer 1: H=4,O=32. row=128 bf16=256B=16 lanes x uint4. 4 edges/sub-round.
__global__ __launch_bounds__(256) void k_agg1(const int* __restrict__ rp, const int* __restrict__ csr,
    const float* __restrict__ as_, const float* __restrict__ ad_,
    const uint4* __restrict__ hb4, const float* __restrict__ bias,
    unsigned short* __restrict__ outb, int N){
  int n = blockIdx.x*4 + (threadIdx.x>>6);
  if (n >= N) return;
  int lane = threadIdx.x & 63;
  int eslot = lane>>2, ehead = lane&3;       // exp duty: edge-slot x head
  int grp = lane>>4, li = lane&15, ghead = li>>2;  // gather duty
  int start = rp[n], end = rp[n+1];
  float adh_e = ad_[n*4+ehead];
  float w_self_e = __expf(fminf(lrelu(as_[n*4+ehead] + adh_e), 80.f));
  float l = (eslot == 0) ? w_self_e : 0.f;   // lanes 0..3 carry self-loop denom
  float a[8];
  #pragma unroll
  for (int k=0;k<8;k++) a[k]=0.f;
  for (int i0 = start; i0 < end; i0 += 16){
    int ei = i0 + eslot;
    int s_e = -1; float w_e = 0.f;
    if (ei < end){
      s_e = csr[ei];
      w_e = __expf(fminf(lrelu(as_[s_e*4+ehead] + adh_e), 80.f));
      l += w_e;
    }
    #pragma unroll
    for (int r=0;r<4;r++){
      int srclane = ((r*4+grp)<<2) | ghead;
      int   s2 = __shfl(s_e, srclane);
      float w2 = __shfl(w_e, srclane);
      if (s2 >= 0){
        uint4 v = hb4[(size_t)s2*16 + li];
        a[0]+=w2*bflo(v.x); a[1]+=w2*bfhi(v.x); a[2]+=w2*bflo(v.y); a[3]+=w2*bfhi(v.y);
        a[4]+=w2*bflo(v.z); a[5]+=w2*bfhi(v.z); a[6]+=w2*bflo(v.w); a[7]+=w2*bfhi(v.w);
      }
    }
  }
  // self-loop row (once per node)
  {
    float w = __shfl(w_self_e, ghead);   // lane g (g<4) holds self-w for head g
    if (grp == 0){
      uint4 v = hb4[(size_t)n*16 + li];
      a[0]+=w*bflo(v.x); a[1]+=w*bfhi(v.x); a[2]+=w*bflo(v.y); a[3]+=w*bfhi(v.y);
      a[4]+=w*bflo(v.z); a[5]+=w*bfhi(v.z); a[6]+=w*bflo(v.w); a[7]+=w*bfhi(v.w);
    }
  }
  // denom: reduce across edge-slots (same ehead)
  l += __shfl_xor(l,4); l += __shfl_xor(l,8); l += __shfl_xor(l,16); l += __shfl_xor(l,32);
  // accum: reduce across the 4 gather groups
  #pragma unroll
  for (int msk=16; msk<64; msk<<=1){
    #pragma unroll
    for (int k=0;k<8;k++) a[k] += __shfl_xor(a[k], msk);
  }
  float denom = __shfl(l, ghead);        // lane g (g<4) holds denom for head g
  if (grp == 0){
    float invh = 1.f/denom;
    float4 b0 = *(const float4*)&bias[li*8];
    float4 b1 = *(const float4*)&bias[li*8+4];
    union { unsigned short us[8]; uint4 v; } pk;
    pk.us[0]=f2bf(eluf(a[0]*invh+b0.x)); pk.us[1]=f2bf(eluf(a[1]*invh+b0.y));
    pk.us[2]=f2bf(eluf(a[2]*invh+b0.z)); pk.us[3]=f2bf(eluf(a[3]*invh+b0.w));
    pk.us[4]=f2bf(eluf(a[4]*invh+b1.x)); pk.us[5]=f2bf(eluf(a[5]*invh+b1.y));
    pk.us[6]=f2bf(eluf(a[6]*invh+b1.z)); pk.us[7]=f2bf(eluf(a[7]*invh+b1.w));
    *(uint4*)&outb[(size_t)n*128 + li*8] = pk.v;
  }
}

// Layer 2: H=2,O=16. row=32 bf16=64B=4 lanes x uint4. 16 edges/sub-round.
__global__ __launch_bounds__(256) void k_agg2(const int* __restrict__ rp, const int* __restrict__ csr,
    const float* __restrict__ as_, const float* __restrict__ ad_,
    const uint4* __restrict__ hb4, const float* __restrict__ bias,
    unsigned short* __restrict__ outb, int N){
  int n = blockIdx.x*4 + (threadIdx.x>>6);
  if (n >= N) return;
  int lane = threadIdx.x & 63;
  int eslot = lane>>1, ehead = lane&1;       // exp duty: 32 edges x 2 heads
  int grp = lane>>2, li = lane&3, ghead = li>>1;  // gather duty
  int start = rp[n], end = rp[n+1];
  float adh_e = ad_[n*2+ehead];
  float w_self_e = __expf(fminf(lrelu(as_[n*2+ehead] + adh_e), 80.f));
  float l = (eslot == 0) ? w_self_e : 0.f;
  float a[8];
  #pragma unroll
  for (int k=0;k<8;k++) a[k]=0.f;
  for (int i0 = start; i0 < end; i0 += 32){
    int ei = i0 + eslot;
    int s_e = -1; float w_e = 0.f;
    if (ei < end){
      s_e = csr[ei];
      w_e = __expf(fminf(lrelu(as_[s_e*2+ehead] + adh_e), 80.f));
      l += w_e;
    }
    #pragma unroll
    for (int r=0;r<2;r++){
      int srclane = ((r*16+grp)<<1) | ghead;
      int   s2 = __shfl(s_e, srclane);
      float w2 = __shfl(w_e, srclane);
      if (s2 >= 0){
        uint4 v = hb4[(size_t)s2*4 + li];
        a[0]+=w2*bflo(v.x); a[1]+=w2*bfhi(v.x); a[2]+=w2*bflo(v.y); a[3]+=w2*bfhi(v.y);
        a[4]+=w2*bflo(v.z); a[5]+=w2*bfhi(v.z); a[6]+=w2*bflo(v.w); a[7]+=w2*bfhi(v.w);
      }
    }
  }
  {
    float w = __shfl(w_self_e, ghead);   // lanes 0,1 hold self-w for heads 0,1
    if (grp == 0){
      uint4 v = hb4[(size_t)n*4 + li];
      a[0]+=w*bflo(v.x); a[1]+=w*bfhi(v.x); a[2]+=w*bflo(v.y); a[3]+=w*bfhi(v.y);
      a[4]+=w*bflo(v.z); a[5]+=w*bfhi(v.z); a[6]+=w*bflo(v.w); a[7]+=w*bfhi(v.w);
    }
  }
  l += __shfl_xor(l,2); l += __shfl_xor(l,4); l += __shfl_xor(l,8);
  l += __shfl_xor(l,16); l += __shfl_xor(l,32);
  #pragma unroll
  for (int msk=4; msk<64; msk<<=1){
    #pragma unroll
    for (int k=0;k<8;k++) a[k] += __shfl_xor(a[k], msk);
  }
  float denom = __shfl(l, ghead);
  if (grp == 0){
    float invh = 1.f/denom;
    float4 b0 = *(const float4*)&bias[li*8];
    float4 b1 = *(const float4*)&bias[li*8+4];
    union { unsigned short us[8]; uint4 v; } pk;
    pk.us[0]=f2bf(eluf(a[0]*invh+b0.x)); pk.us[1]=f2bf(eluf(a[1]*invh+b0.y));
    pk.us[2]=f2bf(eluf(a[2]*invh+b0.z)); pk.us[3]=f2bf(eluf(a[3]*invh+b0.w));
    pk.us[4]=f2bf(eluf(a[4]*invh+b1.x)); pk.us[5]=f2bf(eluf(a[5]*invh+b1.y));
    pk.us[6]=f2bf(eluf(a[6]*invh+b1.z)); pk.us[7]=f2bf(eluf(a[7]*invh+b1.w));
    *(uint4*)&outb[(size_t)n*32 + li*8] = pk.v;
  }
}

// Layer 3: H=1, O=2 (fp32 h). One lane per edge; bias + log_softmax epilogue.
__global__ __launch_bounds__(256) void k_agg3(const int* __restrict__ rp, const int* __restrict__ csr,
    const float* __restrict__ as_, const float* __restrict__ ad_,
    const float* __restrict__ h, const float* __restrict__ bias,
    float* __restrict__ out, int N){
  int n = blockIdx.x*4 + (threadIdx.x>>6);
  if (n >= N) return;
  int lane = threadIdx.x & 63;
  int start = rp[n], end = rp[n+1];
  float adh = ad_[n];
  float sl = lrelu(as_[n] + adh);
  const float2* h2 = (const float2*)h;
  float l = 0.f;
  float2 acc = make_float2(0.f, 0.f);
  for (int i=start+lane; i<end; i+=64){
    int s = csr[i];
    float w = __expf(fminf(lrelu(as_[s] + adh), 80.f));
    l += w;
    float2 v = h2[s];
    acc.x += w*v.x; acc.y += w*v.y;
  }
  if (lane == 0){
    float w = __expf(fminf(sl, 80.f));
    l += w;
    float2 v = h2[n];
    acc.x += w*v.x; acc.y += w*v.y;
  }
  l = wred_sum(l);
  acc.x = wred_sum(acc.x); acc.y = wred_sum(acc.y);
  if (lane == 0){
    float inv = 1.f/l;
    float g0 = acc.x*inv + bias[0];
    float g1 = acc.y*inv + bias[1];
    float mm = fmaxf(g0, g1);
    float lse = mm + logf(__expf(g0-mm) + __expf(g1-mm));
    *(float2*)&out[2*n] = make_float2(g0-lse, g1-lse);
  }
}

// ---------------- launch ----------------
extern "C" void kernel_launch(void* const* d_in, const int* in_sizes, int n_in,
                              void* d_out, int out_size, void* d_ws, size_t ws_size,
                              hipStream_t stream) {
  const float* x   = (const float*)d_in[0];
  const void*  ei  = d_in[1];
  const float* W1  = (const float*)d_in[2];
  const float* as1 = (const float*)d_in[3];
  const float* ad1 = (const float*)d_in[4];
  const float* b1  = (const float*)d_in[5];
  const float* W2  = (const float*)d_in[6];
  const float* as2 = (const float*)d_in[7];
  const float* ad2 = (const float*)d_in[8];
  const float* b2  = (const float*)d_in[9];
  const float* W3  = (const float*)d_in[10];
  const float* as3 = (const float*)d_in[11];
  const float* ad3 = (const float*)d_in[12];
  const float* b3  = (const float*)d_in[13];

  int N = in_sizes[0] / 128;
  int E = in_sizes[1] / 2;
  int NB = (N + 127) >> 7;           // 128 dst per bucket

  char* w = (char*)d_ws;
  size_t off = 0;
  auto alloc = [&](size_t bytes)->void*{
    void* p = w + off; off += (bytes + 255) & ~(size_t)255; return p;
  };
  int*   gbcnt   = (int*)alloc((size_t)NB*4);
  int*   gbbase  = (int*)alloc((size_t)NB*4);
  int*   gcursor = (int*)alloc((size_t)NB*4);
  int*   rp      = (int*)alloc((size_t)(N+1)*4);
  unsigned int* ebuf = (unsigned int*)alloc((size_t)E*4);
  int*   csr     = (int*)alloc((size_t)E*4);
  float* as_buf  = (float*)alloc((size_t)N*4*4);
  float* ad_buf  = (float*)alloc((size_t)N*4*4);
  unsigned short* hb  = (unsigned short*)alloc((size_t)N*128*2); // layer1 h bf16
  unsigned short* xb  = (unsigned short*)alloc((size_t)N*128*2); // layer1 out bf16
  unsigned short* hb2 = (unsigned short*)alloc((size_t)N*32*2);  // layer2 h bf16
  unsigned short* x2b = (unsigned short*)alloc((size_t)N*32*2);  // layer2 out bf16
  float* h3      = (float*)alloc((size_t)N*2*4);                 // layer3 h fp32
  if (off > ws_size) return;  // workspace too small -> visible failure

  hipMemsetAsync(gbcnt, 0, (size_t)NB*4, stream);
  k_bhist<<<256, 256, NB*4, stream>>>(ei, gbcnt, E, NB);
  k_bscan<<<1, 256, 0, stream>>>(gbcnt, gbbase, gcursor, NB);
  int sb = (E + 256*BS_ITEMS - 1) / (256*BS_ITEMS);
  k_bscatter<<<sb, 256, 2*NB*4, stream>>>(ei, gcursor, ebuf, E, NB);
  k_bcsr<<<NB, 256, 0, stream>>>(ebuf, gbbase, gbcnt, rp, csr, N, NB, E);

  // layer 1: Fin=128, H=4, O=32, concat, ELU
  k_gemm1<<<(N + 31)/32, 256, 0, stream>>>(x, W1, hb, N);
  k_attb<4,32><<<(N*4 + 255)/256, 256, 0, stream>>>(hb, as1, ad1, as_buf, ad_buf, N);
  k_agg1<<<(N + 3)/4, 256, 0, stream>>>(rp, csr, as_buf, ad_buf, (const uint4*)hb, b1, xb, N);

  // layer 2: Fin=128, H=2, O=16, concat, ELU
  k_gemm2<<<(N + 63)/64, 128, 0, stream>>>(xb, W2, hb2, N);
  k_attb<2,16><<<(N*2 + 255)/256, 256, 0, stream>>>(hb2, as2, ad2, as_buf, ad_buf, N);
  k_agg2<<<(N + 3)/4, 256, 0, stream>>>(rp, csr, as_buf, ad_buf, (const uint4*)hb2, b2, x2b, N);

  // layer 3: Fin=32, H=1, O=2, mean(=identity), bias + log_softmax
  k_gemm3<<<(N + 255)/256, 256, 0, stream>>>(x2b, W3, as3, ad3, h3, as_buf, ad_buf, N);
  k_agg3<<<(N + 3)/4, 256, 0, stream>>>(rp, csr, as_buf, ad_buf, h3, b3, (float*)d_out, N);
}

// Round 7
// 373.199 us; speedup vs baseline: 1.8300x; 1.1528x over previous
//
#include <hip/hip_runtime.h>
#include <math.h>

// ---------------- helpers ----------------
static __device__ __forceinline__ float lrelu(float x){ return fmaxf(x, 0.2f*x); }
// fast ELU: expm1f is a branchy libm call; __expf(x)-1 differs by ~1ulp(1)=1e-7
static __device__ __forceinline__ float eluf(float x){ return x > 0.f ? x : __expf(x)-1.f; }
static __device__ __forceinline__ float wred_sum(float v){
  v += __shfl_xor(v, 32); v += __shfl_xor(v, 16); v += __shfl_xor(v, 8);
  v += __shfl_xor(v, 4);  v += __shfl_xor(v, 2);  v += __shfl_xor(v, 1);
  return v;
}
static __device__ __forceinline__ unsigned short f2bf(float f){
  unsigned int u = __float_as_uint(f);
  unsigned int r = (u + 0x7FFFu + ((u>>16)&1u)) >> 16;   // round-nearest-even
  return (unsigned short)r;
}
static __device__ __forceinline__ float bflo(unsigned int u){ return __uint_as_float(u<<16); }
static __device__ __forceinline__ float bfhi(unsigned int u){ return __uint_as_float(u & 0xFFFF0000u); }

typedef __attribute__((ext_vector_type(8))) short short8;   // 8 bf16 = 4 VGPR (guide §3)
typedef __attribute__((ext_vector_type(4))) float f32x4;

// ---------------- bucketed CSR build (bucket = dst>>7) ----------------
#define DETECT_IS64(ei_, s_is64_) \
  if (threadIdx.x < 64){ \
    int w_ = ((const int*)(ei_))[2*threadIdx.x + 1]; \
    unsigned long long b_ = __ballot(w_ != 0); \
    if (threadIdx.x == 0) s_is64_ = (b_ == 0ull); \
  } \
  __syncthreads();

__global__ __launch_bounds__(256) void k_bhist(const void* __restrict__ ei,
    int* __restrict__ gbcnt, int E, int NB){
  extern __shared__ int lcnt[];
  __shared__ int s_is64;
  for (int i=threadIdx.x; i<NB; i+=256) lcnt[i]=0;
  DETECT_IS64(ei, s_is64)
  int stride = gridDim.x*256;
  if (s_is64){
    const long long* p = (const long long*)ei;
    for (int e = blockIdx.x*256 + threadIdx.x; e < E; e += stride)
      atomicAdd(&lcnt[((int)p[(size_t)E+e])>>7], 1);
  } else {
    const int* p = (const int*)ei;
    for (int e = blockIdx.x*256 + threadIdx.x; e < E; e += stride)
      atomicAdd(&lcnt[p[(size_t)E+e]>>7], 1);
  }
  __syncthreads();
  for (int i=threadIdx.x; i<NB; i+=256){
    int c = lcnt[i];
    if (c) atomicAdd(&gbcnt[i], c);
  }
}

__global__ __launch_bounds__(256) void k_bscan(const int* __restrict__ gbcnt,
    int* __restrict__ gbbase, int* __restrict__ gcursor, int NB){
  __shared__ int sh[256];
  __shared__ int carry;
  int t = threadIdx.x;
  if (t==0) carry = 0;
  __syncthreads();
  for (int base=0; base<NB; base+=256){
    int idx = base+t;
    int v = (idx<NB)? gbcnt[idx] : 0;
    sh[t]=v; __syncthreads();
    for (int off=1; off<256; off<<=1){
      int add = (t>=off)? sh[t-off] : 0;
      __syncthreads();
      sh[t]+=add;
      __syncthreads();
    }
    int excl = sh[t]-v+carry;
    if (idx<NB){ gbbase[idx]=excl; gcursor[idx]=excl; }
    __syncthreads();
    if (t==0) carry += sh[255];
    __syncthreads();
  }
}

#define BS_ITEMS 16
__global__ __launch_bounds__(256) void k_bscatter(const void* __restrict__ ei,
    int* __restrict__ gcursor, unsigned int* __restrict__ ebuf, int E, int NB){
  extern __shared__ int lds[];     // lcnt[NB] then lbase[NB]
  __shared__ int s_is64;
  int* lcnt = lds; int* lbase = lds + NB;
  for (int i=threadIdx.x; i<NB; i+=256) lcnt[i]=0;
  DETECT_IS64(ei, s_is64)
  bool is64 = s_is64 != 0;
  int base = blockIdx.x*(256*BS_ITEMS);
  unsigned int ent[BS_ITEMS]; int bk[BS_ITEMS];
  #pragma unroll
  for (int i=0;i<BS_ITEMS;i++){
    int e = base + i*256 + threadIdx.x;
    if (e < E){
      int s, d;
      if (is64){ const long long* p=(const long long*)ei; s=(int)p[e]; d=(int)p[(size_t)E+e]; }
      else     { const int* p=(const int*)ei;            s=p[e];      d=p[(size_t)E+e]; }
      int b = d>>7;
      bk[i] = b;
      ent[i] = (unsigned int)s | ((unsigned int)(d & 127) << 25);
      atomicAdd(&lcnt[b], 1);
    } else bk[i] = -1;
  }
  __syncthreads();
  for (int i=threadIdx.x; i<NB; i+=256){
    int c = lcnt[i];
    lbase[i] = c ? atomicAdd(&gcursor[i], c) : 0;
  }
  __syncthreads();
  for (int i=threadIdx.x; i<NB; i+=256) lcnt[i]=0;  // reuse as cursor
  __syncthreads();
  #pragma unroll
  for (int i=0;i<BS_ITEMS;i++){
    if (bk[i] >= 0){
      int pos = lbase[bk[i]] + atomicAdd(&lcnt[bk[i]], 1);
      ebuf[pos] = ent[i];
    }
  }
}

__global__ __launch_bounds__(256) void k_bcsr(const unsigned int* __restrict__ ebuf,
    const int* __restrict__ gbbase, const int* __restrict__ gbcnt,
    int* __restrict__ rp, int* __restrict__ csr, int N, int NB, int E){
  __shared__ int lcnt[128];
  __shared__ int lexc[128];
  __shared__ int lcur[128];
  __shared__ int sc[256];
  int b = blockIdx.x, t = threadIdx.x;
  int d0 = b<<7;
  int R = N - d0; if (R > 128) R = 128;
  if (t < 128){ lcnt[t]=0; lcur[t]=0; }
  __syncthreads();
  int base = gbbase[b], cnt = gbcnt[b];
  for (int i=t; i<cnt; i+=256){
    unsigned int e = ebuf[base+i];
    atomicAdd(&lcnt[e>>25], 1);
  }
  __syncthreads();
  int v = (t<128)? lcnt[t] : 0;
  sc[t]=v; __syncthreads();
  for (int off=1; off<128; off<<=1){
    int add = (t>=off)? sc[t-off] : 0;
    __syncthreads();
    sc[t]+=add;
    __syncthreads();
  }
  if (t<128) lexc[t] = sc[t]-v;
  __syncthreads();
  if (t < R) rp[d0+t] = base + lexc[t];
  if (b == NB-1 && t == 0) rp[N] = E;
  for (int i=t; i<cnt; i+=256){
    unsigned int e = ebuf[base+i];
    int dl = e>>25;
    int pos = base + lexc[dl] + atomicAdd(&lcur[dl], 1);
    csr[pos] = (int)(e & 0x1FFFFFFu);
  }
}

// ------- W pre-pack into MFMA B-fragment order (bf16), once per call -------
// B-frag (16x16x32): lane l holds B[k = (l>>4)*8 + j][n = l&15], j=0..7.
// wf1: [ks:4][ct:8][lane:64][j:8]  (W1 128x128)   wf2: [ks:4][ct:2][lane:64][j:8]
__global__ void k_wprep(const float* __restrict__ W1, const float* __restrict__ W2,
                        unsigned short* __restrict__ wf1, unsigned short* __restrict__ wf2){
  int e = blockIdx.x*256 + threadIdx.x;
  if (e < 2048){
    int lane = e&63, ct = (e>>6)&7, ks = e>>9;
    int q = lane>>4, n = lane&15;
    union { unsigned short us[8]; uint4 u; } pk;
    #pragma unroll
    for (int j=0;j<8;j++)
      pk.us[j] = f2bf(W1[(ks*32 + q*8 + j)*128 + ct*16 + n]);
    *(uint4*)&wf1[(size_t)e*8] = pk.u;
  } else if (e < 2048+512){
    int e2 = e - 2048;
    int lane = e2&63, ct = (e2>>6)&1, ks = e2>>7;
    int q = lane>>4, n = lane&15;
    union { unsigned short us[8]; uint4 u; } pk;
    #pragma unroll
    for (int j=0;j<8;j++)
      pk.us[j] = f2bf(W2[(ks*32 + q*8 + j)*32 + ct*16 + n]);
    *(uint4*)&wf2[(size_t)e2*8] = pk.u;
  }
}

// ------- GEMM1 (MFMA): x(fp32->bf16) @ W1 -> hb bf16, + fused att dots -----
// 64 rows/block, full 128 cols. 4 waves: wave w owns row-tiles {2(w&1),2(w&1)+1},
// col-tiles {4(w>>1)..+3}. A from LDS [m][136-pad]; B from fragment-ordered LDS.
__global__ __launch_bounds__(256) void k_mgemm1(const float* __restrict__ x,
    const unsigned short* __restrict__ wf,
    const float* __restrict__ atts, const float* __restrict__ attd,
    unsigned short* __restrict__ hb, float* __restrict__ as_, float* __restrict__ ad_,
    int N){
  __shared__ unsigned short xs[64*136];    // 17.0 KB: x-tile, later C-tile
  __shared__ unsigned short wsm[2048*8];   // 32 KB: W1 fragments
  int t = threadIdx.x;
  int r0 = blockIdx.x*64;
  { // stage W frags: 2048 uint4 (32 KB) -- was the round-6 bug (only 1024 staged)
    const uint4* src = (const uint4*)wf;
    uint4* dst = (uint4*)wsm;
    #pragma unroll
    for (int i=0;i<8;i++) dst[t + i*256] = src[t + i*256];
  }
  { // stage x tile (fp32 -> bf16): 64 rows x 16 chunks of 8
    #pragma unroll
    for (int i=0;i<4;i++){
      int idx = t + i*256;
      int row = idx>>4, k8 = (idx&15)*8;
      int gr = r0 + row;
      float4 v0 = make_float4(0.f,0.f,0.f,0.f), v1 = v0;
      if (gr < N){
        v0 = *(const float4*)&x[(size_t)gr*128 + k8];
        v1 = *(const float4*)&x[(size_t)gr*128 + k8 + 4];
      }
      union { unsigned short us[8]; uint4 u; } pk;
      pk.us[0]=f2bf(v0.x); pk.us[1]=f2bf(v0.y); pk.us[2]=f2bf(v0.z); pk.us[3]=f2bf(v0.w);
      pk.us[4]=f2bf(v1.x); pk.us[5]=f2bf(v1.y); pk.us[6]=f2bf(v1.z); pk.us[7]=f2bf(v1.w);
      *(uint4*)&xs[row*136 + k8] = pk.u;
    }
  }
  __syncthreads();
  int w = t>>6, lane = t&63, lm = lane&15, q = lane>>4;
  int rt0 = (w&1)*2;
  int ct0 = (w>>1)*4;
  f32x4 acc[2][4];
  #pragma unroll
  for (int a=0;a<2;a++)
    #pragma unroll
    for (int c=0;c<4;c++) acc[a][c] = (f32x4){0.f,0.f,0.f,0.f};
  #pragma unroll
  for (int ks=0;ks<4;ks++){
    short8 a0 = *(const short8*)&xs[( rt0   *16 + lm)*136 + ks*32 + q*8];
    short8 a1 = *(const short8*)&xs[((rt0+1)*16 + lm)*136 + ks*32 + q*8];
    #pragma unroll
    for (int c=0;c<4;c++){
      short8 b = *(const short8*)&wsm[((ks*8 + ct0 + c)*64 + lane)*8];
      acc[0][c] = __builtin_amdgcn_mfma_f32_16x16x32_bf16(a0, b, acc[0][c], 0,0,0);
      acc[1][c] = __builtin_amdgcn_mfma_f32_16x16x32_bf16(a1, b, acc[1][c], 0,0,0);
    }
  }
  __syncthreads();   // xs becomes C-tile
  // C/D layout: col = lane&15, row = (lane>>4)*4 + reg (guide §3, m89/m91)
  #pragma unroll
  for (int rl=0;rl<2;rl++)
    #pragma unroll
    for (int c=0;c<4;c++)
      #pragma unroll
      for (int r=0;r<4;r++)
        xs[((rt0+rl)*16 + q*4 + r)*136 + (ct0+c)*16 + lm] = f2bf(acc[rl][c][r]);
  __syncthreads();
  { // hb writes: 64 rows x 16 uint4
    #pragma unroll
    for (int i=0;i<4;i++){
      int idx = t + i*256;
      int row = idx>>4, c8 = (idx&15)*8;
      int gr = r0 + row;
      if (gr < N)
        *(uint4*)&hb[(size_t)gr*128 + c8] = *(const uint4*)&xs[row*136 + c8];
    }
  }
  { // fused attention dots: 64 rows x 4 heads = 256 pairs
    int row = t>>2, h = t&3;
    int gr = r0 + row;
    if (gr < N){
      const unsigned short* hr = &xs[row*136 + h*32];
      const float* sa = atts + h*32;
      const float* da = attd + h*32;
      float ss = 0.f, dd = 0.f;
      #pragma unroll
      for (int o=0;o<32;o+=8){
        uint4 v = *(const uint4*)&hr[o];
        float hv[8] = { bflo(v.x),bfhi(v.x),bflo(v.y),bfhi(v.y),
                        bflo(v.z),bfhi(v.z),bflo(v.w),bfhi(v.w) };
        #pragma unroll
        for (int m=0;m<8;m++){ ss += hv[m]*sa[o+m]; dd += hv[m]*da[o+m]; }
      }
      as_[gr*4+h] = ss; ad_[gr*4+h] = dd;
    }
  }
}

// ------- GEMM2 (MFMA): xb bf16 @ W2 -> hb2 bf16, + fused att dots ----------
// 128 rows/block, 32 cols. Wave w owns row-tiles {2w,2w+1}, both col-tiles.
__global__ __launch_bounds__(256) void k_mgemm2(const unsigned short* __restrict__ xb,
    const unsigned short* __restrict__ wf,
    const float* __restrict__ atts, const float* __restrict__ attd,
    unsigned short* __restrict__ hb2, float* __restrict__ as_, float* __restrict__ ad_,
    int N){
  __shared__ unsigned short xs[128*136];   // 34 KB: x-tile, later C-tile
  __shared__ unsigned short wsm[512*8];    // 8 KB: W2 fragments
  int t = threadIdx.x;
  int r0 = blockIdx.x*128;
  { // stage W frags: 512 uint4 (8 KB) -- was the round-6 bug (only 256 staged)
    #pragma unroll
    for (int i=0;i<2;i++)
      ((uint4*)wsm)[t + i*256] = ((const uint4*)wf)[t + i*256];
  }
  { // stage x tile (already bf16): 128 rows x 16 uint4
    #pragma unroll
    for (int i=0;i<8;i++){
      int idx = t + i*256;
      int row = idx>>4, c8 = (idx&15)*8;
      int gr = r0 + row;
      uint4 v = make_uint4(0u,0u,0u,0u);
      if (gr < N) v = *(const uint4*)&xb[(size_t)gr*128 + c8];
      *(uint4*)&xs[row*136 + c8] = v;
    }
  }
  __syncthreads();
  int w = t>>6, lane = t&63, lm = lane&15, q = lane>>4;
  int rt0 = 2*w;
  f32x4 acc[2][2];
  #pragma unroll
  for (int a=0;a<2;a++){ acc[a][0] = (f32x4){0.f,0.f,0.f,0.f}; acc[a][1] = acc[a][0]; }
  #pragma unroll
  for (int ks=0;ks<4;ks++){
    short8 a0 = *(const short8*)&xs[( rt0   *16 + lm)*136 + ks*32 + q*8];
    short8 a1 = *(const short8*)&xs[((rt0+1)*16 + lm)*136 + ks*32 + q*8];
    #pragma unroll
    for (int c=0;c<2;c++){
      short8 b = *(const short8*)&wsm[((ks*2 + c)*64 + lane)*8];
      acc[0][c] = __builtin_amdgcn_mfma_f32_16x16x32_bf16(a0, b, acc[0][c], 0,0,0);
      acc[1][c] = __builtin_amdgcn_mfma_f32_16x16x32_bf16(a1, b, acc[1][c], 0,0,0);
    }
  }
  __syncthreads();
  #pragma unroll
  for (int rl=0;rl<2;rl++)
    #pragma unroll
    for (int c=0;c<2;c++)
      #pragma unroll
      for (int r=0;r<4;r++)
        xs[((rt0+rl)*16 + q*4 + r)*136 + c*16 + lm] = f2bf(acc[rl][c][r]);
  __syncthreads();
  { // hb2 writes: 128 rows x 4 uint4
    #pragma unroll
    for (int i=0;i<2;i++){
      int idx = t + i*256;
      int row = idx>>2, c8 = (idx&3)*8;
      int gr = r0 + row;
      if (gr < N)
        *(uint4*)&hb2[(size_t)gr*32 + c8] = *(const uint4*)&xs[row*136 + c8];
    }
  }
  { // fused attention dots: 128 rows x 2 heads = 256 pairs
    int row = t>>1, h = t&1;
    int gr = r0 + row;
    if (gr < N){
      const unsigned short* hr = &xs[row*136 + h*16];
      const float* sa = atts + h*16;
      const float* da = attd + h*16;
      float ss = 0.f, dd = 0.f;
      #pragma unroll
      for (int o=0;o<16;o+=8){
        uint4 v = *(const uint4*)&hr[o];
        float hv[8] = { bflo(v.x),bfhi(v.x),bflo(v.y),bfhi(v.y),
                        bflo(v.z),bfhi(v.z),bflo(v.w),bfhi(v.w) };
        #pragma unroll
        for (int m=0;m<8;m++){ ss += hv[m]*sa[o+m]; dd += hv[m]*da[o+m]; }
      }
      as_[gr*2+h] = ss; ad_[gr*2+h] = dd;
    }
  }
}

// ---------------- GEMM 3: x2b(bf16,32) @ W3(32x2) + att terms -------------
__global__ void k_gemm3(const unsigned short* __restrict__ x2b, const float* __restrict__ W,
                        const float* __restrict__ atts, const float* __restrict__ attd,
                        float* __restrict__ h, float* __restrict__ as_,
                        float* __restrict__ ad_, int N){
  int n = blockIdx.x*blockDim.x + threadIdx.x;
  if (n >= N) return;
  const uint4* xr = (const uint4*)(x2b + (size_t)n*32);
  float a0 = 0.f, a1 = 0.f;
  #pragma unroll
  for (int j=0;j<4;j++){
    uint4 v = xr[j];
    float xv[8] = { bflo(v.x),bfhi(v.x),bflo(v.y),bfhi(v.y),
                    bflo(v.z),bfhi(v.z),bflo(v.w),bfhi(v.w) };
    #pragma unroll
    for (int m=0;m<8;m++){
      int k = j*8+m;
      a0 += xv[m]*W[2*k]; a1 += xv[m]*W[2*k+1];
    }
  }
  h[2*n] = a0; h[2*n+1] = a1;
  as_[n] = a0*atts[0] + a1*atts[1];
  ad_[n] = a0*attd[0] + a1*attd[1];
}

// ---------------- aggregation: single pass, exp-deduplicated --------------
// Layer 1: H=4,O=32. row=128 bf16=256B=16 lanes x uint4. 4 edges/sub-round.
__global__ __launch_bounds__(256) void k_agg1(const int* __restrict__ rp, const int* __restrict__ csr,
    const float* __restrict__ as_, const float* __restrict__ ad_,
    const uint4* __restrict__ hb4, const float* __restrict__ bias,
    unsigned short* __restrict__ outb, int N){
  int n = blockIdx.x*4 + (threadIdx.x>>6);
  if (n >= N) return;
  int lane = threadIdx.x & 63;
  int eslot = lane>>2, ehead = lane&3;       // exp duty: edge-slot x head
  int grp = lane>>4, li = lane&15, ghead = li>>2;  // gather duty
  int start = rp[n], end = rp[n+1];
  float adh_e = ad_[n*4+ehead];
  float w_self_e = __expf(fminf(lrelu(as_[n*4+ehead] + adh_e), 80.f));
  float l = (eslot == 0) ? w_self_e : 0.f;   // lanes 0..3 carry self-loop denom
  float a[8];
  #pragma unroll
  for (int k=0;k<8;k++) a[k]=0.f;
  for (int i0 = start; i0 < end; i0 += 16){
    int ei = i0 + eslot;
    int s_e = -1; float w_e = 0.f;
    if (ei < end){
      s_e = csr[ei];
      w_e = __expf(fminf(lrelu(as_[s_e*4+ehead] + adh_e), 80.f));
      l += w_e;
    }
    #pragma unroll
    for (int r=0;r<4;r++){
      int srclane = ((r*4+grp)<<2) | ghead;
      int   s2 = __shfl(s_e, srclane);
      float w2 = __shfl(w_e, srclane);
      if (s2 >= 0){
        uint4 v = hb4[(size_t)s2*16 + li];
        a[0]+=w2*bflo(v.x); a[1]+=w2*bfhi(v.x); a[2]+=w2*bflo(v.y); a[3]+=w2*bfhi(v.y);
        a[4]+=w2*bflo(v.z); a[5]+=w2*bfhi(v.z); a[6]+=w2*bflo(v.w); a[7]+=w2*bfhi(v.w);
      }
    }
  }
  { // self-loop row
    float w = __shfl(w_self_e, ghead);
    if (grp == 0){
      uint4 v = hb4[(size_t)n*16 + li];
      a[0]+=w*bflo(v.x); a[1]+=w*bfhi(v.x); a[2]+=w*bflo(v.y); a[3]+=w*bfhi(v.y);
      a[4]+=w*bflo(v.z); a[5]+=w*bfhi(v.z); a[6]+=w*bflo(v.w); a[7]+=w*bfhi(v.w);
    }
  }
  l += __shfl_xor(l,4); l += __shfl_xor(l,8); l += __shfl_xor(l,16); l += __shfl_xor(l,32);
  #pragma unroll
  for (int msk=16; msk<64; msk<<=1){
    #pragma unroll
    for (int k=0;k<8;k++) a[k] += __shfl_xor(a[k], msk);
  }
  float denom = __shfl(l, ghead);
  if (grp == 0){
    float invh = 1.f/denom;
    float4 b0 = *(const float4*)&bias[li*8];
    float4 b1 = *(const float4*)&bias[li*8+4];
    union { unsigned short us[8]; uint4 v; } pk;
    pk.us[0]=f2bf(eluf(a[0]*invh+b0.x)); pk.us[1]=f2bf(eluf(a[1]*invh+b0.y));
    pk.us[2]=f2bf(eluf(a[2]*invh+b0.z)); pk.us[3]=f2bf(eluf(a[3]*invh+b0.w));
    pk.us[4]=f2bf(eluf(a[4]*invh+b1.x)); pk.us[5]=f2bf(eluf(a[5]*invh+b1.y));
    pk.us[6]=f2bf(eluf(a[6]*invh+b1.z)); pk.us[7]=f2bf(eluf(a[7]*invh+b1.w));
    *(uint4*)&outb[(size_t)n*128 + li*8] = pk.v;
  }
}

// Layer 2: H=2,O=16. row=32 bf16=64B=4 lanes x uint4. 16 edges/sub-round.
__global__ __launch_bounds__(256) void k_agg2(const int* __restrict__ rp, const int* __restrict__ csr,
    const float* __restrict__ as_, const float* __restrict__ ad_,
    const uint4* __restrict__ hb4, const float* __restrict__ bias,
    unsigned short* __restrict__ outb, int N){
  int n = blockIdx.x*4 + (threadIdx.x>>6);
  if (n >= N) return;
  int lane = threadIdx.x & 63;
  int eslot = lane>>1, ehead = lane&1;
  int grp = lane>>2, li = lane&3, ghead = li>>1;
  int start = rp[n], end = rp[n+1];
  float adh_e = ad_[n*2+ehead];
  float w_self_e = __expf(fminf(lrelu(as_[n*2+ehead] + adh_e), 80.f));
  float l = (eslot == 0) ? w_self_e : 0.f;
  float a[8];
  #pragma unroll
  for (int k=0;k<8;k++) a[k]=0.f;
  for (int i0 = start; i0 < end; i0 += 32){
    int ei = i0 + eslot;
    int s_e = -1; float w_e = 0.f;
    if (ei < end){
      s_e = csr[ei];
      w_e = __expf(fminf(lrelu(as_[s_e*2+ehead] + adh_e), 80.f));
      l += w_e;
    }
    #pragma unroll
    for (int r=0;r<2;r++){
      int srclane = ((r*16+grp)<<1) | ghead;
      int   s2 = __shfl(s_e, srclane);
      float w2 = __shfl(w_e, srclane);
      if (s2 >= 0){
        uint4 v = hb4[(size_t)s2*4 + li];
        a[0]+=w2*bflo(v.x); a[1]+=w2*bfhi(v.x); a[2]+=w2*bflo(v.y); a[3]+=w2*bfhi(v.y);
        a[4]+=w2*bflo(v.z); a[5]+=w2*bfhi(v.z); a[6]+=w2*bflo(v.w); a[7]+=w2*bfhi(v.w);
      }
    }
  }
  {
    float w = __shfl(w_self_e, ghead);
    if (grp == 0){
      uint4 v = hb4[(size_t)n*4 + li];
      a[0]+=w*bflo(v.x); a[1]+=w*bfhi(v.x); a[2]+=w*bflo(v.y); a[3]+=w*bfhi(v.y);
      a[4]+=w*bflo(v.z); a[5]+=w*bfhi(v.z); a[6]+=w*bflo(v.w); a[7]+=w*bfhi(v.w);
    }
  }
  l += __shfl_xor(l,2); l += __shfl_xor(l,4); l += __shfl_xor(l,8);
  l += __shfl_xor(l,16); l += __shfl_xor(l,32);
  #pragma unroll
  for (int msk=4; msk<64; msk<<=1){
    #pragma unroll
    for (int k=0;k<8;k++) a[k] += __shfl_xor(a[k], msk);
  }
  float denom = __shfl(l, ghead);
  if (grp == 0){
    float invh = 1.f/denom;
    float4 b0 = *(const float4*)&bias[li*8];
    float4 b1 = *(const float4*)&bias[li*8+4];
    union { unsigned short us[8]; uint4 v; } pk;
    pk.us[0]=f2bf(eluf(a[0]*invh+b0.x)); pk.us[1]=f2bf(eluf(a[1]*invh+b0.y));
    pk.us[2]=f2bf(eluf(a[2]*invh+b0.z)); pk.us[3]=f2bf(eluf(a[3]*invh+b0.w));
    pk.us[4]=f2bf(eluf(a[4]*invh+b1.x)); pk.us[5]=f2bf(eluf(a[5]*invh+b1.y));
    pk.us[6]=f2bf(eluf(a[6]*invh+b1.z)); pk.us[7]=f2bf(eluf(a[7]*invh+b1.w));
    *(uint4*)&outb[(size_t)n*32 + li*8] = pk.v;
  }
}

// Layer 3: H=1, O=2 (fp32 h). One lane per edge; bias + log_softmax epilogue.
__global__ __launch_bounds__(256) void k_agg3(const int* __restrict__ rp, const int* __restrict__ csr,
    const float* __restrict__ as_, const float* __restrict__ ad_,
    const float* __restrict__ h, const float* __restrict__ bias,
    float* __restrict__ out, int N){
  int n = blockIdx.x*4 + (threadIdx.x>>6);
  if (n >= N) return;
  int lane = threadIdx.x & 63;
  int start = rp[n], end = rp[n+1];
  float adh = ad_[n];
  float sl = lrelu(as_[n] + adh);
  const float2* h2 = (const float2*)h;
  float l = 0.f;
  float2 acc = make_float2(0.f, 0.f);
  for (int i=start+lane; i<end; i+=64){
    int s = csr[i];
    float w = __expf(fminf(lrelu(as_[s] + adh), 80.f));
    l += w;
    float2 v = h2[s];
    acc.x += w*v.x; acc.y += w*v.y;
  }
  if (lane == 0){
    float w = __expf(fminf(sl, 80.f));
    l += w;
    float2 v = h2[n];
    acc.x += w*v.x; acc.y += w*v.y;
  }
  l = wred_sum(l);
  acc.x = wred_sum(acc.x); acc.y = wred_sum(acc.y);
  if (lane == 0){
    float inv = 1.f/l;
    float g0 = acc.x*inv + bias[0];
    float g1 = acc.y*inv + bias[1];
    float mm = fmaxf(g0, g1);
    float lse = mm + logf(__expf(g0-mm) + __expf(g1-mm));
    *(float2*)&out[2*n] = make_float2(g0-lse, g1-lse);
  }
}

// ---------------- launch ----------------
extern "C" void kernel_launch(void* const* d_in, const int* in_sizes, int n_in,
                              void* d_out, int out_size, void* d_ws, size_t ws_size,
                              hipStream_t stream) {
  const float* x   = (const float*)d_in[0];
  const void*  ei  = d_in[1];
  const float* W1  = (const float*)d_in[2];
  const float* as1 = (const float*)d_in[3];
  const float* ad1 = (const float*)d_in[4];
  const float* b1  = (const float*)d_in[5];
  const float* W2  = (const float*)d_in[6];
  const float* as2 = (const float*)d_in[7];
  const float* ad2 = (const float*)d_in[8];
  const float* b2  = (const float*)d_in[9];
  const float* W3  = (const float*)d_in[10];
  const float* as3 = (const float*)d_in[11];
  const float* ad3 = (const float*)d_in[12];
  const float* b3  = (const float*)d_in[13];

  int N = in_sizes[0] / 128;
  int E = in_sizes[1] / 2;
  int NB = (N + 127) >> 7;           // 128 dst per bucket

  char* w = (char*)d_ws;
  size_t off = 0;
  auto alloc = [&](size_t bytes)->void*{
    void* p = w + off; off += (bytes + 255) & ~(size_t)255; return p;
  };
  int*   gbcnt   = (int*)alloc((size_t)NB*4);
  int*   gbbase  = (int*)alloc((size_t)NB*4);
  int*   gcursor = (int*)alloc((size_t)NB*4);
  int*   rp      = (int*)alloc((size_t)(N+1)*4);
  unsigned int* ebuf = (unsigned int*)alloc((size_t)E*4);
  int*   csr     = (int*)alloc((size_t)E*4);
  float* as_buf  = (float*)alloc((size_t)N*4*4);
  float* ad_buf  = (float*)alloc((size_t)N*4*4);
  unsigned short* wf1 = (unsigned short*)alloc(2048*8*2);        // W1 frags bf16
  unsigned short* wf2 = (unsigned short*)alloc(512*8*2);         // W2 frags bf16
  unsigned short* hb  = (unsigned short*)alloc((size_t)N*128*2); // layer1 h bf16
  unsigned short* xb  = (unsigned short*)alloc((size_t)N*128*2); // layer1 out bf16
  unsigned short* hb2 = (unsigned short*)alloc((size_t)N*32*2);  // layer2 h bf16
  unsigned short* x2b = (unsigned short*)alloc((size_t)N*32*2);  // layer2 out bf16
  float* h3      = (float*)alloc((size_t)N*2*4);                 // layer3 h fp32
  if (off > ws_size) return;  // workspace too small -> visible failure

  hipMemsetAsync(gbcnt, 0, (size_t)NB*4, stream);
  k_wprep<<<10, 256, 0, stream>>>(W1, W2, wf1, wf2);
  k_bhist<<<256, 256, NB*4, stream>>>(ei, gbcnt, E, NB);
  k_bscan<<<1, 256, 0, stream>>>(gbcnt, gbbase, gcursor, NB);
  int sb = (E + 256*BS_ITEMS - 1) / (256*BS_ITEMS);
  k_bscatter<<<sb, 256, 2*NB*4, stream>>>(ei, gcursor, ebuf, E, NB);
  k_bcsr<<<NB, 256, 0, stream>>>(ebuf, gbbase, gbcnt, rp, csr, N, NB, E);

  // layer 1: Fin=128, H=4, O=32, concat, ELU  (MFMA + fused att epilogue)
  k_mgemm1<<<(N + 63)/64, 256, 0, stream>>>(x, wf1, as1, ad1, hb, as_buf, ad_buf, N);
  k_agg1<<<(N + 3)/4, 256, 0, stream>>>(rp, csr, as_buf, ad_buf, (const uint4*)hb, b1, xb, N);

  // layer 2: Fin=128, H=2, O=16, concat, ELU  (MFMA + fused att epilogue)
  k_mgemm2<<<(N + 127)/128, 256, 0, stream>>>(xb, wf2, as2, ad2, hb2, as_buf, ad_buf, N);
  k_agg2<<<(N + 3)/4, 256, 0, stream>>>(rp, csr, as_buf, ad_buf, (const uint4*)hb2, b2, x2b, N);

  // layer 3: Fin=32, H=1, O=2, mean(=identity), bias + log_softmax
  k_gemm3<<<(N + 255)/256, 256, 0, stream>>>(x2b, W3, as3, ad3, h3, as_buf, ad_buf, N);
  k_agg3<<<(N + 3)/4, 256, 0, stream>>>(rp, csr, as_buf, ad_buf, h3, b3, (float*)d_out, N);
}